// Round 1
// baseline (518.339 us; speedup 1.0000x reference)
//
#include <hip/hip_runtime.h>

#define N_NODES 100000
#define N_EDGES 1600000
#define IN_F 32
#define HID_F 64
#define OUT_F 16

// -------- scatter layer 1: agg1[dst] += feat[src], deg[dst] += 1 --------
__global__ __launch_bounds__(256) void scatter1_kernel(
    const int* __restrict__ src, const int* __restrict__ dst,
    const float* __restrict__ feat,
    float* __restrict__ agg1, float* __restrict__ deg) {
  long long tid = (long long)blockIdx.x * blockDim.x + threadIdx.x;
  if (tid >= (long long)N_EDGES * IN_F) return;
  int e = (int)(tid >> 5);   // edge index
  int f = (int)(tid & 31);   // feature index
  int s = src[e];
  int d = dst[e];
  float val = feat[s * IN_F + f];
  atomicAdd(&agg1[d * IN_F + f], val);
  if (f == 0) atomicAdd(&deg[d], 1.0f);
}

// -------- layer 1: h1 = relu(feat @ W1s + (agg1/deg) @ W1n + b1) --------
__global__ __launch_bounds__(256) void layer1_kernel(
    const float* __restrict__ feat, const float* __restrict__ agg1,
    const float* __restrict__ deg,
    const float* __restrict__ W1s, const float* __restrict__ W1n,
    const float* __restrict__ b1, float* __restrict__ h1) {
  __shared__ float sWs[IN_F * HID_F];
  __shared__ float sWn[IN_F * HID_F];
  __shared__ float sb[HID_F];
  for (int i = threadIdx.x; i < IN_F * HID_F; i += blockDim.x) {
    sWs[i] = W1s[i];
    sWn[i] = W1n[i];
  }
  if (threadIdx.x < HID_F) sb[threadIdx.x] = b1[threadIdx.x];
  __syncthreads();

  int gid = blockIdx.x * blockDim.x + threadIdx.x;
  int v = gid >> 6;        // node
  int j = gid & 63;        // hidden unit
  if (v >= N_NODES) return;
  float r = 1.0f / fmaxf(deg[v], 1.0f);
  float acc = sb[j];
  const float* frow = feat + v * IN_F;
  const float* arow = agg1 + v * IN_F;
#pragma unroll
  for (int k = 0; k < IN_F; ++k) {
    acc += frow[k] * sWs[k * HID_F + j] + (arow[k] * r) * sWn[k * HID_F + j];
  }
  h1[v * HID_F + j] = fmaxf(acc, 0.0f);
}

// -------- t2 = h1 @ W2_neigh  (pre-transform before aggregation) --------
__global__ __launch_bounds__(256) void t2_kernel(
    const float* __restrict__ h1, const float* __restrict__ W2n,
    float* __restrict__ t2) {
  __shared__ float sW[HID_F * OUT_F];
  for (int i = threadIdx.x; i < HID_F * OUT_F; i += blockDim.x) sW[i] = W2n[i];
  __syncthreads();

  int gid = blockIdx.x * blockDim.x + threadIdx.x;
  int v = gid >> 4;
  int j = gid & 15;
  if (v >= N_NODES) return;
  const float* hrow = h1 + v * HID_F;
  float acc = 0.0f;
#pragma unroll
  for (int k = 0; k < HID_F; ++k) acc += hrow[k] * sW[k * OUT_F + j];
  t2[v * OUT_F + j] = acc;
}

// -------- scatter layer 2: agg2[dst] += t2[src] --------
__global__ __launch_bounds__(256) void scatter2_kernel(
    const int* __restrict__ src, const int* __restrict__ dst,
    const float* __restrict__ t2, float* __restrict__ agg2) {
  long long tid = (long long)blockIdx.x * blockDim.x + threadIdx.x;
  if (tid >= (long long)N_EDGES * OUT_F) return;
  int e = (int)(tid >> 4);
  int f = (int)(tid & 15);
  int s = src[e];
  int d = dst[e];
  atomicAdd(&agg2[d * OUT_F + f], t2[s * OUT_F + f]);
}

// -------- final: out = h1 @ W2s + agg2/deg + b2 --------
__global__ __launch_bounds__(256) void final_kernel(
    const float* __restrict__ h1, const float* __restrict__ agg2,
    const float* __restrict__ deg,
    const float* __restrict__ W2s, const float* __restrict__ b2,
    float* __restrict__ out) {
  __shared__ float sW[HID_F * OUT_F];
  __shared__ float sb[OUT_F];
  for (int i = threadIdx.x; i < HID_F * OUT_F; i += blockDim.x) sW[i] = W2s[i];
  if (threadIdx.x < OUT_F) sb[threadIdx.x] = b2[threadIdx.x];
  __syncthreads();

  int gid = blockIdx.x * blockDim.x + threadIdx.x;
  int v = gid >> 4;
  int j = gid & 15;
  if (v >= N_NODES) return;
  float r = 1.0f / fmaxf(deg[v], 1.0f);
  const float* hrow = h1 + v * HID_F;
  float acc = sb[j] + agg2[v * OUT_F + j] * r;
#pragma unroll
  for (int k = 0; k < HID_F; ++k) acc += hrow[k] * sW[k * OUT_F + j];
  out[v * OUT_F + j] = acc;
}

extern "C" void kernel_launch(void* const* d_in, const int* in_sizes, int n_in,
                              void* d_out, int out_size, void* d_ws, size_t ws_size,
                              hipStream_t stream) {
  const float* feat = (const float*)d_in[0];
  const int* src    = (const int*)d_in[1];
  const int* dst    = (const int*)d_in[2];
  const float* W1s  = (const float*)d_in[3];
  const float* W1n  = (const float*)d_in[4];
  const float* b1   = (const float*)d_in[5];
  const float* W2s  = (const float*)d_in[6];
  const float* W2n  = (const float*)d_in[7];
  const float* b2   = (const float*)d_in[8];
  float* out = (float*)d_out;

  const long long N = N_NODES;
  float* ws = (float*)d_ws;
  float* deg  = ws;            // [N]
  float* agg1 = ws + N;        // [N,32]   region [N, 33N)
  float* h1   = ws + 33 * N;   // [N,64]
  // after layer1, agg1's region is reused:
  float* t2   = ws + N;        // [N,16]   region [N, 17N)
  float* agg2 = ws + 17 * N;   // [N,16]   region [17N, 33N)

  // zero deg + agg1 (33N floats)
  hipMemsetAsync(deg, 0, 33 * N * sizeof(float), stream);

  {
    long long total = (long long)N_EDGES * IN_F;
    int blocks = (int)((total + 255) / 256);
    scatter1_kernel<<<blocks, 256, 0, stream>>>(src, dst, feat, agg1, deg);
  }
  {
    int blocks = (int)((N * HID_F + 255) / 256);
    layer1_kernel<<<blocks, 256, 0, stream>>>(feat, agg1, deg, W1s, W1n, b1, h1);
  }
  // zero agg2 (16N floats) — safe: layer1 has consumed agg1
  hipMemsetAsync(agg2, 0, 16 * N * sizeof(float), stream);
  {
    int blocks = (int)((N * OUT_F + 255) / 256);
    t2_kernel<<<blocks, 256, 0, stream>>>(h1, W2n, t2);
  }
  {
    long long total = (long long)N_EDGES * OUT_F;
    int blocks = (int)((total + 255) / 256);
    scatter2_kernel<<<blocks, 256, 0, stream>>>(src, dst, t2, agg2);
  }
  {
    int blocks = (int)((N * OUT_F + 255) / 256);
    final_kernel<<<blocks, 256, 0, stream>>>(h1, agg2, deg, W2s, b2, out);
  }
}

// Round 2
// 460.208 us; speedup vs baseline: 1.1263x; 1.1263x over previous
//
#include <hip/hip_runtime.h>

#define N_NODES 100000
#define N_EDGES 1600000
#define IN_F 32
#define HID_F 64
#define OUT_F 16
#define NB ((N_NODES + 255) / 256)   // 391 blocks for node-sized scans

// ---------------- CSR build ----------------

__global__ __launch_bounds__(256) void count_kernel(
    const int* __restrict__ dst, int* __restrict__ cnt) {
  int e = blockIdx.x * 256 + threadIdx.x;
  if (e < N_EDGES) atomicAdd(&cnt[dst[e]], 1);
}

// block sums of cnt
__global__ __launch_bounds__(256) void scan1_kernel(
    const int* __restrict__ cnt, int* __restrict__ bsum) {
  __shared__ int red[256];
  int i = blockIdx.x * 256 + threadIdx.x;
  red[threadIdx.x] = (i < N_NODES) ? cnt[i] : 0;
  __syncthreads();
  for (int s = 128; s > 0; s >>= 1) {
    if (threadIdx.x < s) red[threadIdx.x] += red[threadIdx.x + s];
    __syncthreads();
  }
  if (threadIdx.x == 0) bsum[blockIdx.x] = red[0];
}

// exclusive scan of the 391 block sums (single block, 512 threads)
__global__ __launch_bounds__(512) void scan2_kernel(
    const int* __restrict__ bsum, int* __restrict__ bscan) {
  __shared__ int sh[512];
  int t = threadIdx.x;
  sh[t] = (t < NB) ? bsum[t] : 0;
  __syncthreads();
  for (int off = 1; off < 512; off <<= 1) {
    int v = (t >= off) ? sh[t - off] : 0;
    __syncthreads();
    sh[t] += v;
    __syncthreads();
  }
  if (t < NB) bscan[t] = (t == 0) ? 0 : sh[t - 1];
}

// per-element exclusive scan: ptr[i] = bscan[b] + excl_scan_in_block(cnt)
__global__ __launch_bounds__(256) void scan3_kernel(
    const int* __restrict__ cnt, const int* __restrict__ bscan,
    int* __restrict__ ptr) {
  __shared__ int sh[256];
  int t = threadIdx.x;
  int i = blockIdx.x * 256 + t;
  int v = (i < N_NODES) ? cnt[i] : 0;
  sh[t] = v;
  __syncthreads();
  for (int off = 1; off < 256; off <<= 1) {
    int u = (t >= off) ? sh[t - off] : 0;
    __syncthreads();
    sh[t] += u;
    __syncthreads();
  }
  if (i < N_NODES) ptr[i] = bscan[blockIdx.x] + sh[t] - v;  // exclusive
}

// fill CSR; destructive on ptr: afterwards ptr[v] == end(v) == start(v+1)
__global__ __launch_bounds__(256) void fill_kernel(
    const int* __restrict__ src, const int* __restrict__ dst,
    int* __restrict__ ptr, int* __restrict__ col) {
  int e = blockIdx.x * 256 + threadIdx.x;
  if (e < N_EDGES) {
    int p = atomicAdd(&ptr[dst[e]], 1);
    col[p] = src[e];
  }
}

// ---------------- layer 1 aggregate (gather, no atomics) ----------------
// meanf[v][f] = mean of feat[src][f] over incoming edges. 32 lanes per node.
__global__ __launch_bounds__(256) void gather1_kernel(
    const int* __restrict__ ptr, const int* __restrict__ col,
    const float* __restrict__ feat, float* __restrict__ meanf) {
  int gid = blockIdx.x * 256 + threadIdx.x;
  int v = gid >> 5;
  int f = gid & 31;
  int start = (v == 0) ? 0 : ptr[v - 1];
  int end = ptr[v];
  float s0 = 0.f, s1 = 0.f, s2 = 0.f, s3 = 0.f;
  int e = start;
  for (; e + 3 < end; e += 4) {
    int c0 = col[e], c1 = col[e + 1], c2 = col[e + 2], c3 = col[e + 3];
    s0 += feat[c0 * IN_F + f];
    s1 += feat[c1 * IN_F + f];
    s2 += feat[c2 * IN_F + f];
    s3 += feat[c3 * IN_F + f];
  }
  for (; e < end; ++e) s0 += feat[col[e] * IN_F + f];
  float sum = (s0 + s1) + (s2 + s3);
  meanf[v * IN_F + f] = sum / fmaxf((float)(end - start), 1.0f);
}

// ---------------- layer 1 + both layer-2 transforms, fused ----------------
// Per node: h1 = relu(feat@W1s + meanf@W1n + b1) (kept in LDS only),
// then t2 = h1@W2n, s2 = h1@W2s. h1 never touches global memory.
__global__ __launch_bounds__(256) void layer1_fused_kernel(
    const float* __restrict__ feat, const float* __restrict__ meanf,
    const float* __restrict__ W1s, const float* __restrict__ W1n,
    const float* __restrict__ b1,
    const float* __restrict__ W2s, const float* __restrict__ W2n,
    float* __restrict__ t2, float* __restrict__ s2) {
  __shared__ float sWs[IN_F * HID_F];    // 2048
  __shared__ float sWn[IN_F * HID_F];    // 2048
  __shared__ float sW2n[HID_F * OUT_F];  // 1024
  __shared__ float sW2s[HID_F * OUT_F];  // 1024
  __shared__ float sb1[HID_F];
  __shared__ float sh[4 * HID_F];   // h1 for 4 nodes
  __shared__ float sin_[4 * IN_F];  // self feats
  __shared__ float smn[4 * IN_F];   // mean feats

  int t = threadIdx.x;
  for (int i = t; i < IN_F * HID_F; i += 256) { sWs[i] = W1s[i]; sWn[i] = W1n[i]; }
  for (int i = t; i < HID_F * OUT_F; i += 256) { sW2n[i] = W2n[i]; sW2s[i] = W2s[i]; }
  if (t < HID_F) sb1[t] = b1[t];
  if (t < 128) sin_[t] = feat[blockIdx.x * 4 * IN_F + t];
  else smn[t - 128] = meanf[blockIdx.x * 4 * IN_F + (t - 128)];
  __syncthreads();

  int nl = t >> 6;   // 0..3 node within block
  int j = t & 63;
  float acc = sb1[j];
#pragma unroll
  for (int k = 0; k < IN_F; ++k) {
    acc += sin_[nl * IN_F + k] * sWs[k * HID_F + j]
         + smn[nl * IN_F + k] * sWn[k * HID_F + j];
  }
  sh[nl * HID_F + j] = fmaxf(acc, 0.0f);
  __syncthreads();

  int v = blockIdx.x * 4 + nl;
  if (j < OUT_F) {                      // t2 = h1 @ W2n
    float a = 0.f;
#pragma unroll
    for (int k = 0; k < HID_F; ++k) a += sh[nl * HID_F + k] * sW2n[k * OUT_F + j];
    t2[v * OUT_F + j] = a;
  } else if (j < 2 * OUT_F) {           // s2 = h1 @ W2s
    int jj = j - OUT_F;
    float a = 0.f;
#pragma unroll
    for (int k = 0; k < HID_F; ++k) a += sh[nl * HID_F + k] * sW2s[k * OUT_F + jj];
    s2[v * OUT_F + jj] = a;
  }
}

// ---------------- layer 2 aggregate + final output, fused ----------------
// out[v][j] = s2[v][j] + b2[j] + (sum_e t2[col][j]) / max(deg,1)
__global__ __launch_bounds__(256) void gather2_final_kernel(
    const int* __restrict__ ptr, const int* __restrict__ col,
    const float* __restrict__ t2, const float* __restrict__ s2,
    const float* __restrict__ b2, float* __restrict__ out) {
  int gid = blockIdx.x * 256 + threadIdx.x;
  int v = gid >> 4;
  int j = gid & 15;
  int start = (v == 0) ? 0 : ptr[v - 1];
  int end = ptr[v];
  float a0 = 0.f, a1 = 0.f, a2 = 0.f, a3 = 0.f;
  int e = start;
  for (; e + 3 < end; e += 4) {
    int c0 = col[e], c1 = col[e + 1], c2 = col[e + 2], c3 = col[e + 3];
    a0 += t2[c0 * OUT_F + j];
    a1 += t2[c1 * OUT_F + j];
    a2 += t2[c2 * OUT_F + j];
    a3 += t2[c3 * OUT_F + j];
  }
  for (; e < end; ++e) a0 += t2[col[e] * OUT_F + j];
  float sum = (a0 + a1) + (a2 + a3);
  out[v * OUT_F + j] = s2[v * OUT_F + j] + b2[j]
                     + sum / fmaxf((float)(end - start), 1.0f);
}

extern "C" void kernel_launch(void* const* d_in, const int* in_sizes, int n_in,
                              void* d_out, int out_size, void* d_ws, size_t ws_size,
                              hipStream_t stream) {
  const float* feat = (const float*)d_in[0];
  const int* src    = (const int*)d_in[1];
  const int* dst    = (const int*)d_in[2];
  const float* W1s  = (const float*)d_in[3];
  const float* W1n  = (const float*)d_in[4];
  const float* b1   = (const float*)d_in[5];
  const float* W2s  = (const float*)d_in[6];
  const float* W2n  = (const float*)d_in[7];
  const float* b2   = (const float*)d_in[8];
  float* out = (float*)d_out;

  const int N = N_NODES;
  // workspace layout (32.8 MB total)
  int* cnt = (int*)d_ws;               // N
  int* ptr = cnt + N;                  // N+1 (uses N)
  int* col = ptr + N + 8;              // E
  float* meanf = (float*)(col + N_EDGES);  // 32N
  float* t2 = meanf + 32 * (size_t)N;      // 16N
  float* s2 = t2 + 16 * (size_t)N;         // 16N
  int* bsum = (int*)(s2 + 16 * (size_t)N); // NB
  int* bscan = bsum + 512;                 // NB

  hipMemsetAsync(cnt, 0, N * sizeof(int), stream);

  count_kernel<<<(N_EDGES + 255) / 256, 256, 0, stream>>>(dst, cnt);
  scan1_kernel<<<NB, 256, 0, stream>>>(cnt, bsum);
  scan2_kernel<<<1, 512, 0, stream>>>(bsum, bscan);
  scan3_kernel<<<NB, 256, 0, stream>>>(cnt, bscan, ptr);
  fill_kernel<<<(N_EDGES + 255) / 256, 256, 0, stream>>>(src, dst, ptr, col);

  gather1_kernel<<<N * IN_F / 256, 256, 0, stream>>>(ptr, col, feat, meanf);
  layer1_fused_kernel<<<N / 4, 256, 0, stream>>>(feat, meanf, W1s, W1n, b1,
                                                 W2s, W2n, t2, s2);
  gather2_final_kernel<<<N * OUT_F / 256, 256, 0, stream>>>(ptr, col, t2, s2,
                                                            b2, out);
}

// Round 3
// 392.551 us; speedup vs baseline: 1.3204x; 1.1724x over previous
//
#include <hip/hip_runtime.h>

#define N_NODES 100000
#define N_EDGES 1600000
#define IN_F 32
#define HID_F 64
#define OUT_F 16
#define NB ((N_NODES + 255) / 256)   // 391 blocks for node-sized scans

// ---------------- CSR build ----------------

__global__ __launch_bounds__(256) void count_kernel(
    const int* __restrict__ dst, int* __restrict__ cnt) {
  int e = blockIdx.x * 256 + threadIdx.x;
  if (e < N_EDGES) atomicAdd(&cnt[dst[e]], 1);
}

__global__ __launch_bounds__(256) void scan1_kernel(
    const int* __restrict__ cnt, int* __restrict__ bsum) {
  __shared__ int red[256];
  int i = blockIdx.x * 256 + threadIdx.x;
  red[threadIdx.x] = (i < N_NODES) ? cnt[i] : 0;
  __syncthreads();
  for (int s = 128; s > 0; s >>= 1) {
    if (threadIdx.x < s) red[threadIdx.x] += red[threadIdx.x + s];
    __syncthreads();
  }
  if (threadIdx.x == 0) bsum[blockIdx.x] = red[0];
}

__global__ __launch_bounds__(512) void scan2_kernel(
    const int* __restrict__ bsum, int* __restrict__ bscan) {
  __shared__ int sh[512];
  int t = threadIdx.x;
  sh[t] = (t < NB) ? bsum[t] : 0;
  __syncthreads();
  for (int off = 1; off < 512; off <<= 1) {
    int v = (t >= off) ? sh[t - off] : 0;
    __syncthreads();
    sh[t] += v;
    __syncthreads();
  }
  if (t < NB) bscan[t] = (t == 0) ? 0 : sh[t - 1];
}

__global__ __launch_bounds__(256) void scan3_kernel(
    const int* __restrict__ cnt, const int* __restrict__ bscan,
    int* __restrict__ ptr) {
  __shared__ int sh[256];
  int t = threadIdx.x;
  int i = blockIdx.x * 256 + t;
  int v = (i < N_NODES) ? cnt[i] : 0;
  sh[t] = v;
  __syncthreads();
  for (int off = 1; off < 256; off <<= 1) {
    int u = (t >= off) ? sh[t - off] : 0;
    __syncthreads();
    sh[t] += u;
    __syncthreads();
  }
  if (i < N_NODES) ptr[i] = bscan[blockIdx.x] + sh[t] - v;  // exclusive
}

// destructive on ptr: afterwards ptr[v] == end(v)
__global__ __launch_bounds__(256) void fill_kernel(
    const int* __restrict__ src, const int* __restrict__ dst,
    int* __restrict__ ptr, int* __restrict__ col) {
  int e = blockIdx.x * 256 + threadIdx.x;
  if (e < N_EDGES) {
    int p = atomicAdd(&ptr[dst[e]], 1);
    col[p] = src[e];
  }
}

// ---------------- layer 1 aggregate: float4 gather, 8 lanes/node ----------------
__global__ __launch_bounds__(256) void gather1_kernel(
    const int* __restrict__ ptr, const int* __restrict__ col,
    const float* __restrict__ feat, float* __restrict__ meanf) {
  int gid = blockIdx.x * 256 + threadIdx.x;
  int v = gid >> 3;
  int f4 = gid & 7;
  int start = (v == 0) ? 0 : ptr[v - 1];
  int end = ptr[v];
  const float4* F = (const float4*)feat;
  float4 s0 = {0.f, 0.f, 0.f, 0.f}, s1 = {0.f, 0.f, 0.f, 0.f};
  int e = start;
  for (; e + 1 < end; e += 2) {
    int c0 = col[e], c1 = col[e + 1];
    float4 a = F[c0 * 8 + f4];
    float4 b = F[c1 * 8 + f4];
    s0.x += a.x; s0.y += a.y; s0.z += a.z; s0.w += a.w;
    s1.x += b.x; s1.y += b.y; s1.z += b.z; s1.w += b.w;
  }
  if (e < end) {
    float4 a = F[col[e] * 8 + f4];
    s0.x += a.x; s0.y += a.y; s0.z += a.z; s0.w += a.w;
  }
  float inv = 1.0f / fmaxf((float)(end - start), 1.0f);
  float4 r;
  r.x = (s0.x + s1.x) * inv; r.y = (s0.y + s1.y) * inv;
  r.z = (s0.z + s1.z) * inv; r.w = (s0.w + s1.w) * inv;
  ((float4*)meanf)[v * 8 + f4] = r;
}

// ------- fused: h1 = relu(feat@W1s + meanf@W1n + b1) in LDS; t2=h1@W2n, s2=h1@W2s -------
// Weights live in registers (column per lane). Feature rows read with
// wave-uniform float4 loads (single 16B L2 transaction, broadcast).
__global__ __launch_bounds__(256) void l1t2s2_kernel(
    const float* __restrict__ feat, const float* __restrict__ meanf,
    const float* __restrict__ W1s, const float* __restrict__ W1n,
    const float* __restrict__ b1,
    const float* __restrict__ W2n, const float* __restrict__ W2s,
    float* __restrict__ t2, float* __restrict__ s2) {
  __shared__ float sh1[64 * HID_F];  // 16 KB: h1 tile for 64 nodes

  int t = threadIdx.x;
  int j = t & 63;
  int wv = t >> 6;  // wave in block, 0..3

  // phase-1 weights: column j of W1s/W1n
  float ws[IN_F], wn[IN_F];
#pragma unroll
  for (int k = 0; k < IN_F; ++k) {
    ws[k] = W1s[k * HID_F + j];
    wn[k] = W1n[k * HID_F + j];
  }
  float bj = b1[j];

  // phase-2 weights: lanes 0-15 = W2n col, 16-31 = W2s col (repeats in upper half)
  int oc = t & 31;
  int c = oc & 15;
  const float* W2 = (oc < 16) ? W2n : W2s;
  float w2[HID_F];
#pragma unroll
  for (int k = 0; k < HID_F; ++k) w2[k] = W2[k * OUT_F + c];

  int tile = blockIdx.x * 64;

  // ---- phase 1: 16 nodes per wave ----
  for (int i = 0; i < 16; ++i) {
    int nl = wv + 4 * i;       // local node 0..63
    int v = tile + nl;
    if (v < N_NODES) {
      const float4* f4 = (const float4*)(feat + (size_t)v * IN_F);
      const float4* m4 = (const float4*)(meanf + (size_t)v * IN_F);
      float acc = bj;
#pragma unroll
      for (int q = 0; q < 8; ++q) {
        float4 a = f4[q];
        float4 b = m4[q];
        acc += a.x * ws[4 * q] + a.y * ws[4 * q + 1] + a.z * ws[4 * q + 2] + a.w * ws[4 * q + 3];
        acc += b.x * wn[4 * q] + b.y * wn[4 * q + 1] + b.z * wn[4 * q + 2] + b.w * wn[4 * q + 3];
      }
      sh1[nl * HID_F + j] = fmaxf(acc, 0.0f);
    }
  }
  __syncthreads();

  // ---- phase 2: 2 nodes per wave-iter (half-waves), 8 iters ----
  int half = (t >> 5) & 1;
  for (int i = 0; i < 8; ++i) {
    int p = wv + 4 * i;        // pair 0..31
    int nl = 2 * p + half;
    int v = tile + nl;
    if (v < N_NODES) {
      const float4* h4 = (const float4*)(sh1 + nl * HID_F);
      float acc = 0.0f;
#pragma unroll
      for (int q = 0; q < 16; ++q) {
        float4 a = h4[q];
        acc += a.x * w2[4 * q] + a.y * w2[4 * q + 1] + a.z * w2[4 * q + 2] + a.w * w2[4 * q + 3];
      }
      if (oc < 16) t2[v * OUT_F + c] = acc;
      else         s2[v * OUT_F + c] = acc;
    }
  }
}

// ---------------- layer 2 aggregate + final: float4, 4 lanes/node ----------------
__global__ __launch_bounds__(256) void gather2_final_kernel(
    const int* __restrict__ ptr, const int* __restrict__ col,
    const float* __restrict__ t2, const float* __restrict__ s2,
    const float* __restrict__ b2, float* __restrict__ out) {
  int gid = blockIdx.x * 256 + threadIdx.x;
  int v = gid >> 2;
  int c4 = gid & 3;
  if (v >= N_NODES) return;
  int start = (v == 0) ? 0 : ptr[v - 1];
  int end = ptr[v];
  const float4* T = (const float4*)t2;
  float4 a0 = {0.f, 0.f, 0.f, 0.f}, a1 = {0.f, 0.f, 0.f, 0.f};
  int e = start;
  for (; e + 1 < end; e += 2) {
    int c0 = col[e], c1 = col[e + 1];
    float4 x = T[c0 * 4 + c4];
    float4 y = T[c1 * 4 + c4];
    a0.x += x.x; a0.y += x.y; a0.z += x.z; a0.w += x.w;
    a1.x += y.x; a1.y += y.y; a1.z += y.z; a1.w += y.w;
  }
  if (e < end) {
    float4 x = T[col[e] * 4 + c4];
    a0.x += x.x; a0.y += x.y; a0.z += x.z; a0.w += x.w;
  }
  float inv = 1.0f / fmaxf((float)(end - start), 1.0f);
  float4 sv = ((const float4*)s2)[v * 4 + c4];
  float4 bv = ((const float4*)b2)[c4];
  float4 r;
  r.x = sv.x + bv.x + (a0.x + a1.x) * inv;
  r.y = sv.y + bv.y + (a0.y + a1.y) * inv;
  r.z = sv.z + bv.z + (a0.z + a1.z) * inv;
  r.w = sv.w + bv.w + (a0.w + a1.w) * inv;
  ((float4*)out)[v * 4 + c4] = r;
}

extern "C" void kernel_launch(void* const* d_in, const int* in_sizes, int n_in,
                              void* d_out, int out_size, void* d_ws, size_t ws_size,
                              hipStream_t stream) {
  const float* feat = (const float*)d_in[0];
  const int* src    = (const int*)d_in[1];
  const int* dst    = (const int*)d_in[2];
  const float* W1s  = (const float*)d_in[3];
  const float* W1n  = (const float*)d_in[4];
  const float* b1   = (const float*)d_in[5];
  const float* W2s  = (const float*)d_in[6];
  const float* W2n  = (const float*)d_in[7];
  const float* b2   = (const float*)d_in[8];
  float* out = (float*)d_out;

  const int N = N_NODES;
  // workspace layout (~32.8 MB)
  int* cnt = (int*)d_ws;                    // N
  int* ptr = cnt + N;                       // N (+8 pad)
  int* col = ptr + N + 8;                   // E
  float* meanf = (float*)(col + N_EDGES);   // 32N
  float* t2 = meanf + 32 * (size_t)N;       // 16N
  float* s2 = t2 + 16 * (size_t)N;          // 16N
  int* bsum = (int*)(s2 + 16 * (size_t)N);  // 512
  int* bscan = bsum + 512;                  // 512

  hipMemsetAsync(cnt, 0, N * sizeof(int), stream);

  count_kernel<<<(N_EDGES + 255) / 256, 256, 0, stream>>>(dst, cnt);
  scan1_kernel<<<NB, 256, 0, stream>>>(cnt, bsum);
  scan2_kernel<<<1, 512, 0, stream>>>(bsum, bscan);
  scan3_kernel<<<NB, 256, 0, stream>>>(cnt, bscan, ptr);
  fill_kernel<<<(N_EDGES + 255) / 256, 256, 0, stream>>>(src, dst, ptr, col);

  gather1_kernel<<<N * 8 / 256, 256, 0, stream>>>(ptr, col, feat, meanf);
  l1t2s2_kernel<<<(N + 63) / 64, 256, 0, stream>>>(feat, meanf, W1s, W1n, b1,
                                                   W2n, W2s, t2, s2);
  gather2_final_kernel<<<(N * 4 + 255) / 256, 256, 0, stream>>>(ptr, col, t2, s2,
                                                                b2, out);
}

// Round 4
// 360.490 us; speedup vs baseline: 1.4379x; 1.0889x over previous
//
#include <hip/hip_runtime.h>

#define N_NODES 100000
#define N_EDGES 1600000
#define IN_F 32
#define HID_F 64
#define OUT_F 16
#define NB ((N_NODES + 255) / 256)   // 391 blocks for node-sized scans
#define NBKT 128                     // buckets (98 used), bucket = dst >> 10
#define CHUNK 4096                   // edges per block in bucket pass

// ---------------- CSR build ----------------

__global__ __launch_bounds__(256) void count_kernel(
    const int* __restrict__ dst, int* __restrict__ cnt) {
  int e = blockIdx.x * 256 + threadIdx.x;
  if (e < N_EDGES) atomicAdd(&cnt[dst[e]], 1);
}

__global__ __launch_bounds__(256) void scan1_kernel(
    const int* __restrict__ cnt, int* __restrict__ bsum) {
  __shared__ int red[256];
  int i = blockIdx.x * 256 + threadIdx.x;
  red[threadIdx.x] = (i < N_NODES) ? cnt[i] : 0;
  __syncthreads();
  for (int s = 128; s > 0; s >>= 1) {
    if (threadIdx.x < s) red[threadIdx.x] += red[threadIdx.x + s];
    __syncthreads();
  }
  if (threadIdx.x == 0) bsum[blockIdx.x] = red[0];
}

__global__ __launch_bounds__(512) void scan2_kernel(
    const int* __restrict__ bsum, int* __restrict__ bscan) {
  __shared__ int sh[512];
  int t = threadIdx.x;
  sh[t] = (t < NB) ? bsum[t] : 0;
  __syncthreads();
  for (int off = 1; off < 512; off <<= 1) {
    int v = (t >= off) ? sh[t - off] : 0;
    __syncthreads();
    sh[t] += v;
    __syncthreads();
  }
  if (t < NB) bscan[t] = (t == 0) ? 0 : sh[t - 1];
}

__global__ __launch_bounds__(256) void scan3_kernel(
    const int* __restrict__ cnt, const int* __restrict__ bscan,
    int* __restrict__ ptr) {
  __shared__ int sh[256];
  int t = threadIdx.x;
  int i = blockIdx.x * 256 + t;
  int v = (i < N_NODES) ? cnt[i] : 0;
  sh[t] = v;
  __syncthreads();
  for (int off = 1; off < 256; off <<= 1) {
    int u = (t >= off) ? sh[t - off] : 0;
    __syncthreads();
    sh[t] += u;
    __syncthreads();
  }
  if (i < N_NODES) ptr[i] = bscan[blockIdx.x] + sh[t] - v;  // exclusive
}

// cursor[b] = edge offset of bucket b = exclusive ptr at node (b<<10)
__global__ __launch_bounds__(128) void cursor_init_kernel(
    const int* __restrict__ ptr, int* __restrict__ cursor) {
  int t = threadIdx.x;
  int node = t << 10;
  cursor[t] = (node < N_NODES) ? ptr[node] : N_EDGES;
}

// one-pass LDS-staged bucket sort of edges by dst>>10 → sorted[] (dst,src pairs)
__global__ __launch_bounds__(256) void bucket_kernel(
    const int* __restrict__ src, const int* __restrict__ dst,
    int* __restrict__ cursor, uint2* __restrict__ sorted) {
  __shared__ uint2 stage[CHUNK];         // 32 KB
  __shared__ int lcnt[NBKT], lscan[NBKT], gbase[NBKT];
  int t = threadIdx.x;
  for (int i = t; i < NBKT; i += 256) lcnt[i] = 0;
  __syncthreads();

  int base = blockIdx.x * CHUNK;
  uint2 mypair[CHUNK / 256];
  int myb[CHUNK / 256], myrank[CHUNK / 256];
#pragma unroll
  for (int i = 0; i < CHUNK / 256; ++i) {
    int e = base + t + 256 * i;
    if (e < N_EDGES) {
      int s = src[e], d = dst[e];
      mypair[i].x = (unsigned)s;
      mypair[i].y = (unsigned)d;
      myb[i] = d >> 10;
      myrank[i] = atomicAdd(&lcnt[myb[i]], 1);
    } else {
      myb[i] = -1;
    }
  }
  __syncthreads();
  // inclusive scan of lcnt -> lscan
  if (t < NBKT) lscan[t] = lcnt[t];
  __syncthreads();
  for (int off = 1; off < NBKT; off <<= 1) {
    int v = (t < NBKT && t >= off) ? lscan[t - off] : 0;
    __syncthreads();
    if (t < NBKT) lscan[t] += v;
    __syncthreads();
  }
  if (t < NBKT) gbase[t] = lcnt[t] ? atomicAdd(&cursor[t], lcnt[t]) : 0;
  __syncthreads();
  // stage pairs ordered by bucket
#pragma unroll
  for (int i = 0; i < CHUNK / 256; ++i) {
    if (myb[i] >= 0) {
      int slot = (lscan[myb[i]] - lcnt[myb[i]]) + myrank[i];
      stage[slot] = mypair[i];
    }
  }
  __syncthreads();
  // coalesced-run copy to global
  int nvalid = min(CHUNK, N_EDGES - base);
  for (int i = t; i < nvalid; i += 256) {
    uint2 p = stage[i];
    int b = (int)(p.y >> 10);
    int addr = gbase[b] + (i - (lscan[b] - lcnt[b]));
    sorted[addr] = p;
  }
}

// exact fill from bucket-sorted edges; destructive on ptr: afterwards ptr[v]==end(v)
__global__ __launch_bounds__(256) void fill2_kernel(
    const uint2* __restrict__ sorted, int* __restrict__ ptr,
    int* __restrict__ col) {
  int e = blockIdx.x * 256 + threadIdx.x;
  if (e < N_EDGES) {
    uint2 p = sorted[e];
    int pos = atomicAdd(&ptr[p.y], 1);
    col[pos] = (int)p.x;
  }
}

// ---------------- layer 1 aggregate: float4 gather, 8 lanes/node ----------------
__global__ __launch_bounds__(256) void gather1_kernel(
    const int* __restrict__ ptr, const int* __restrict__ col,
    const float* __restrict__ feat, float* __restrict__ meanf) {
  int gid = blockIdx.x * 256 + threadIdx.x;
  int v = gid >> 3;
  int f4 = gid & 7;
  int start = (v == 0) ? 0 : ptr[v - 1];
  int end = ptr[v];
  const float4* F = (const float4*)feat;
  float4 s0 = {0.f, 0.f, 0.f, 0.f}, s1 = {0.f, 0.f, 0.f, 0.f};
  int e = start;
  for (; e + 1 < end; e += 2) {
    int c0 = col[e], c1 = col[e + 1];
    float4 a = F[c0 * 8 + f4];
    float4 b = F[c1 * 8 + f4];
    s0.x += a.x; s0.y += a.y; s0.z += a.z; s0.w += a.w;
    s1.x += b.x; s1.y += b.y; s1.z += b.z; s1.w += b.w;
  }
  if (e < end) {
    float4 a = F[col[e] * 8 + f4];
    s0.x += a.x; s0.y += a.y; s0.z += a.z; s0.w += a.w;
  }
  float inv = 1.0f / fmaxf((float)(end - start), 1.0f);
  float4 r;
  r.x = (s0.x + s1.x) * inv; r.y = (s0.y + s1.y) * inv;
  r.z = (s0.z + s1.z) * inv; r.w = (s0.w + s1.w) * inv;
  ((float4*)meanf)[v * 8 + f4] = r;
}

// ------- fused: h1 = relu(feat@W1s + meanf@W1n + b1) in LDS; t2=h1@W2n, s2=h1@W2s -------
__global__ __launch_bounds__(256) void l1t2s2_kernel(
    const float* __restrict__ feat, const float* __restrict__ meanf,
    const float* __restrict__ W1s, const float* __restrict__ W1n,
    const float* __restrict__ b1,
    const float* __restrict__ W2n, const float* __restrict__ W2s,
    float* __restrict__ t2, float* __restrict__ s2) {
  __shared__ float sh1[64 * HID_F];  // 16 KB: h1 tile for 64 nodes

  int t = threadIdx.x;
  int j = t & 63;
  int wv = t >> 6;

  float ws[IN_F], wn[IN_F];
#pragma unroll
  for (int k = 0; k < IN_F; ++k) {
    ws[k] = W1s[k * HID_F + j];
    wn[k] = W1n[k * HID_F + j];
  }
  float bj = b1[j];

  int oc = t & 31;
  int c = oc & 15;
  const float* W2 = (oc < 16) ? W2n : W2s;
  float w2[HID_F];
#pragma unroll
  for (int k = 0; k < HID_F; ++k) w2[k] = W2[k * OUT_F + c];

  int tile = blockIdx.x * 64;

  for (int i = 0; i < 16; ++i) {
    int nl = wv + 4 * i;
    int v = tile + nl;
    if (v < N_NODES) {
      const float4* f4 = (const float4*)(feat + (size_t)v * IN_F);
      const float4* m4 = (const float4*)(meanf + (size_t)v * IN_F);
      float acc = bj;
#pragma unroll
      for (int q = 0; q < 8; ++q) {
        float4 a = f4[q];
        float4 b = m4[q];
        acc += a.x * ws[4 * q] + a.y * ws[4 * q + 1] + a.z * ws[4 * q + 2] + a.w * ws[4 * q + 3];
        acc += b.x * wn[4 * q] + b.y * wn[4 * q + 1] + b.z * wn[4 * q + 2] + b.w * wn[4 * q + 3];
      }
      sh1[nl * HID_F + j] = fmaxf(acc, 0.0f);
    }
  }
  __syncthreads();

  int half = (t >> 5) & 1;
  for (int i = 0; i < 8; ++i) {
    int p = wv + 4 * i;
    int nl = 2 * p + half;
    int v = tile + nl;
    if (v < N_NODES) {
      const float4* h4 = (const float4*)(sh1 + nl * HID_F);
      float acc = 0.0f;
#pragma unroll
      for (int q = 0; q < 16; ++q) {
        float4 a = h4[q];
        acc += a.x * w2[4 * q] + a.y * w2[4 * q + 1] + a.z * w2[4 * q + 2] + a.w * w2[4 * q + 3];
      }
      if (oc < 16) t2[v * OUT_F + c] = acc;
      else         s2[v * OUT_F + c] = acc;
    }
  }
}

// ---------------- layer 2 aggregate + final: float4, 4 lanes/node ----------------
__global__ __launch_bounds__(256) void gather2_final_kernel(
    const int* __restrict__ ptr, const int* __restrict__ col,
    const float* __restrict__ t2, const float* __restrict__ s2,
    const float* __restrict__ b2, float* __restrict__ out) {
  int gid = blockIdx.x * 256 + threadIdx.x;
  int v = gid >> 2;
  int c4 = gid & 3;
  if (v >= N_NODES) return;
  int start = (v == 0) ? 0 : ptr[v - 1];
  int end = ptr[v];
  const float4* T = (const float4*)t2;
  float4 a0 = {0.f, 0.f, 0.f, 0.f}, a1 = {0.f, 0.f, 0.f, 0.f};
  int e = start;
  for (; e + 1 < end; e += 2) {
    int c0 = col[e], c1 = col[e + 1];
    float4 x = T[c0 * 4 + c4];
    float4 y = T[c1 * 4 + c4];
    a0.x += x.x; a0.y += x.y; a0.z += x.z; a0.w += x.w;
    a1.x += y.x; a1.y += y.y; a1.z += y.z; a1.w += y.w;
  }
  if (e < end) {
    float4 x = T[col[e] * 4 + c4];
    a0.x += x.x; a0.y += x.y; a0.z += x.z; a0.w += x.w;
  }
  float inv = 1.0f / fmaxf((float)(end - start), 1.0f);
  float4 sv = ((const float4*)s2)[v * 4 + c4];
  float4 bv = ((const float4*)b2)[c4];
  float4 r;
  r.x = sv.x + bv.x + (a0.x + a1.x) * inv;
  r.y = sv.y + bv.y + (a0.y + a1.y) * inv;
  r.z = sv.z + bv.z + (a0.z + a1.z) * inv;
  r.w = sv.w + bv.w + (a0.w + a1.w) * inv;
  ((float4*)out)[v * 4 + c4] = r;
}

extern "C" void kernel_launch(void* const* d_in, const int* in_sizes, int n_in,
                              void* d_out, int out_size, void* d_ws, size_t ws_size,
                              hipStream_t stream) {
  const float* feat = (const float*)d_in[0];
  const int* src    = (const int*)d_in[1];
  const int* dst    = (const int*)d_in[2];
  const float* W1s  = (const float*)d_in[3];
  const float* W1n  = (const float*)d_in[4];
  const float* b1   = (const float*)d_in[5];
  const float* W2s  = (const float*)d_in[6];
  const float* W2n  = (const float*)d_in[7];
  const float* b2   = (const float*)d_in[8];
  float* out = (float*)d_out;

  const int N = N_NODES;
  // workspace layout (~33 MB). sorted[] aliases meanf[] (consumed before gather1).
  int* cnt = (int*)d_ws;                    // N
  int* ptr = cnt + N;                       // N (+8 pad)
  int* col = ptr + N + 8;                   // E
  float* meanf = (float*)(col + N_EDGES);   // 32N floats
  uint2* sorted = (uint2*)meanf;            // E pairs (12.8MB) — fits in 32N floats
  float* t2 = meanf + 32 * (size_t)N;       // 16N
  float* s2 = t2 + 16 * (size_t)N;          // 16N
  int* bsum = (int*)(s2 + 16 * (size_t)N);  // 512
  int* bscan = bsum + 512;                  // 512
  int* cursor = bscan + 512;                // 128

  hipMemsetAsync(cnt, 0, N * sizeof(int), stream);

  count_kernel<<<(N_EDGES + 255) / 256, 256, 0, stream>>>(dst, cnt);
  scan1_kernel<<<NB, 256, 0, stream>>>(cnt, bsum);
  scan2_kernel<<<1, 512, 0, stream>>>(bsum, bscan);
  scan3_kernel<<<NB, 256, 0, stream>>>(cnt, bscan, ptr);
  cursor_init_kernel<<<1, 128, 0, stream>>>(ptr, cursor);
  bucket_kernel<<<(N_EDGES + CHUNK - 1) / CHUNK, 256, 0, stream>>>(src, dst, cursor, sorted);
  fill2_kernel<<<(N_EDGES + 255) / 256, 256, 0, stream>>>(sorted, ptr, col);

  gather1_kernel<<<N * 8 / 256, 256, 0, stream>>>(ptr, col, feat, meanf);
  l1t2s2_kernel<<<(N + 63) / 64, 256, 0, stream>>>(feat, meanf, W1s, W1n, b1,
                                                   W2n, W2s, t2, s2);
  gather2_final_kernel<<<(N * 4 + 255) / 256, 256, 0, stream>>>(ptr, col, t2, s2,
                                                                b2, out);
}

// Round 5
// 337.119 us; speedup vs baseline: 1.5376x; 1.0693x over previous
//
#include <hip/hip_runtime.h>

#define N_NODES 100000
#define N_EDGES 1600000
#define IN_F 32
#define HID_F 64
#define OUT_F 16
#define NB ((N_NODES + 255) / 256)   // 391 blocks for node-sized scans
#define NBKT 128                     // buckets (98 used), bucket = dst >> 10
#define CHUNK 4096                   // edges per block in bucket pass

// ---------------- CSR build ----------------

__global__ __launch_bounds__(256) void count_kernel(
    const int* __restrict__ dst, int* __restrict__ cnt) {
  int e = blockIdx.x * 256 + threadIdx.x;
  if (e < N_EDGES) atomicAdd(&cnt[dst[e]], 1);
}

__global__ __launch_bounds__(256) void scan1_kernel(
    const int* __restrict__ cnt, int* __restrict__ bsum) {
  __shared__ int red[256];
  int i = blockIdx.x * 256 + threadIdx.x;
  red[threadIdx.x] = (i < N_NODES) ? cnt[i] : 0;
  __syncthreads();
  for (int s = 128; s > 0; s >>= 1) {
    if (threadIdx.x < s) red[threadIdx.x] += red[threadIdx.x + s];
    __syncthreads();
  }
  if (threadIdx.x == 0) bsum[blockIdx.x] = red[0];
}

__global__ __launch_bounds__(512) void scan2_kernel(
    const int* __restrict__ bsum, int* __restrict__ bscan) {
  __shared__ int sh[512];
  int t = threadIdx.x;
  sh[t] = (t < NB) ? bsum[t] : 0;
  __syncthreads();
  for (int off = 1; off < 512; off <<= 1) {
    int v = (t >= off) ? sh[t - off] : 0;
    __syncthreads();
    sh[t] += v;
    __syncthreads();
  }
  if (t < NB) bscan[t] = (t == 0) ? 0 : sh[t - 1];
}

__global__ __launch_bounds__(256) void scan3_kernel(
    const int* __restrict__ cnt, const int* __restrict__ bscan,
    int* __restrict__ ptr) {
  __shared__ int sh[256];
  int t = threadIdx.x;
  int i = blockIdx.x * 256 + t;
  int v = (i < N_NODES) ? cnt[i] : 0;
  sh[t] = v;
  __syncthreads();
  for (int off = 1; off < 256; off <<= 1) {
    int u = (t >= off) ? sh[t - off] : 0;
    __syncthreads();
    sh[t] += u;
    __syncthreads();
  }
  if (i < N_NODES) ptr[i] = bscan[blockIdx.x] + sh[t] - v;  // exclusive
}

// cursor[b] = edge offset of bucket b = exclusive ptr at node (b<<10)
__global__ __launch_bounds__(128) void cursor_init_kernel(
    const int* __restrict__ ptr, int* __restrict__ cursor) {
  int t = threadIdx.x;
  int node = t << 10;
  cursor[t] = (node < N_NODES) ? ptr[node] : N_EDGES;
}

// one-pass LDS-staged bucket sort of edges by dst>>10 → sorted[] (src,dst pairs)
__global__ __launch_bounds__(256) void bucket_kernel(
    const int* __restrict__ src, const int* __restrict__ dst,
    int* __restrict__ cursor, uint2* __restrict__ sorted) {
  __shared__ uint2 stage[CHUNK];         // 32 KB
  __shared__ int lcnt[NBKT], lscan[NBKT], gbase[NBKT];
  int t = threadIdx.x;
  for (int i = t; i < NBKT; i += 256) lcnt[i] = 0;
  __syncthreads();

  int base = blockIdx.x * CHUNK;
  uint2 mypair[CHUNK / 256];
  int myb[CHUNK / 256], myrank[CHUNK / 256];
#pragma unroll
  for (int i = 0; i < CHUNK / 256; ++i) {
    int e = base + t + 256 * i;
    if (e < N_EDGES) {
      int s = src[e], d = dst[e];
      mypair[i].x = (unsigned)s;
      mypair[i].y = (unsigned)d;
      myb[i] = d >> 10;
      myrank[i] = atomicAdd(&lcnt[myb[i]], 1);
    } else {
      myb[i] = -1;
    }
  }
  __syncthreads();
  if (t < NBKT) lscan[t] = lcnt[t];
  __syncthreads();
  for (int off = 1; off < NBKT; off <<= 1) {
    int v = (t < NBKT && t >= off) ? lscan[t - off] : 0;
    __syncthreads();
    if (t < NBKT) lscan[t] += v;
    __syncthreads();
  }
  if (t < NBKT) gbase[t] = lcnt[t] ? atomicAdd(&cursor[t], lcnt[t]) : 0;
  __syncthreads();
#pragma unroll
  for (int i = 0; i < CHUNK / 256; ++i) {
    if (myb[i] >= 0) {
      int slot = (lscan[myb[i]] - lcnt[myb[i]]) + myrank[i];
      stage[slot] = mypair[i];
    }
  }
  __syncthreads();
  int nvalid = min(CHUNK, N_EDGES - base);
  for (int i = t; i < nvalid; i += 256) {
    uint2 p = stage[i];
    int b = (int)(p.y >> 10);
    int addr = gbase[b] + (i - (lscan[b] - lcnt[b]));
    sorted[addr] = p;
  }
}

// exact fill from bucket-sorted edges; destructive on ptr: afterwards ptr[v]==end(v)
__global__ __launch_bounds__(256) void fill2_kernel(
    const uint2* __restrict__ sorted, int* __restrict__ ptr,
    int* __restrict__ col) {
  int e = blockIdx.x * 256 + threadIdx.x;
  if (e < N_EDGES) {
    uint2 p = sorted[e];
    int pos = atomicAdd(&ptr[p.y], 1);
    col[pos] = (int)p.x;
  }
}

// ---------------- layer 1 aggregate: float4 gather, 8 lanes/node ----------------
__global__ __launch_bounds__(256) void gather1_kernel(
    const int* __restrict__ ptr, const int* __restrict__ col,
    const float* __restrict__ feat, float* __restrict__ meanf) {
  int gid = blockIdx.x * 256 + threadIdx.x;
  int v = gid >> 3;
  int f4 = gid & 7;
  int start = (v == 0) ? 0 : ptr[v - 1];
  int end = ptr[v];
  const float4* F = (const float4*)feat;
  float4 s0 = {0.f, 0.f, 0.f, 0.f}, s1 = {0.f, 0.f, 0.f, 0.f};
  int e = start;
  for (; e + 1 < end; e += 2) {
    int c0 = col[e], c1 = col[e + 1];
    float4 a = F[c0 * 8 + f4];
    float4 b = F[c1 * 8 + f4];
    s0.x += a.x; s0.y += a.y; s0.z += a.z; s0.w += a.w;
    s1.x += b.x; s1.y += b.y; s1.z += b.z; s1.w += b.w;
  }
  if (e < end) {
    float4 a = F[col[e] * 8 + f4];
    s0.x += a.x; s0.y += a.y; s0.z += a.z; s0.w += a.w;
  }
  float inv = 1.0f / fmaxf((float)(end - start), 1.0f);
  float4 r;
  r.x = (s0.x + s1.x) * inv; r.y = (s0.y + s1.y) * inv;
  r.z = (s0.z + s1.z) * inv; r.w = (s0.w + s1.w) * inv;
  ((float4*)meanf)[v * 8 + f4] = r;
}

// ------- fused: h1 = relu(feat@W1s + meanf@W1n + b1) in LDS; t2=h1@W2n, s2=h1@W2s -------
// v2: feat/meanf tile staged in LDS via coalesced float4 loads; phase-1 compute
// reads LDS broadcasts. w2 columns loaded AFTER phase-1 barrier to cut live regs.
__global__ __launch_bounds__(256) void l1t2s2_kernel(
    const float* __restrict__ feat, const float* __restrict__ meanf,
    const float* __restrict__ W1s, const float* __restrict__ W1n,
    const float* __restrict__ b1,
    const float* __restrict__ W2n, const float* __restrict__ W2s,
    float* __restrict__ t2, float* __restrict__ s2) {
  __shared__ float sfeat[64 * IN_F];   // 8 KB
  __shared__ float smean[64 * IN_F];   // 8 KB
  __shared__ float sh1[64 * HID_F];    // 16 KB

  int t = threadIdx.x;
  int tile = blockIdx.x * 64;
  int nvalid = min(64, N_NODES - tile);

  // coalesced stage: 64 rows x 32 floats = 512 float4 each
  {
    const float4* Fg = (const float4*)(feat + (size_t)tile * IN_F);
    const float4* Mg = (const float4*)(meanf + (size_t)tile * IN_F);
    float4* Fs = (float4*)sfeat;
    float4* Ms = (float4*)smean;
    int lim = nvalid * 8;
#pragma unroll
    for (int i = 0; i < 2; ++i) {
      int idx = t + 256 * i;
      if (idx < lim) { Fs[idx] = Fg[idx]; Ms[idx] = Mg[idx]; }
    }
  }

  // phase-1 weights: column j (lane-varying, coalesced)
  int j = t & 63;
  float ws[IN_F], wn[IN_F];
#pragma unroll
  for (int k = 0; k < IN_F; ++k) {
    ws[k] = W1s[k * HID_F + j];
    wn[k] = W1n[k * HID_F + j];
  }
  float bj = b1[j];
  __syncthreads();

  // ---- phase 1: each wave computes 16 contiguous nodes from LDS ----
  int wv = t >> 6;
#pragma unroll 2
  for (int i = 0; i < 16; ++i) {
    int nl = wv * 16 + i;
    const float4* f4 = (const float4*)(sfeat + nl * IN_F);
    const float4* m4 = (const float4*)(smean + nl * IN_F);
    float acc = bj;
#pragma unroll
    for (int q = 0; q < 8; ++q) {
      float4 a = f4[q];
      float4 b = m4[q];
      acc += a.x * ws[4 * q] + a.y * ws[4 * q + 1] + a.z * ws[4 * q + 2] + a.w * ws[4 * q + 3];
      acc += b.x * wn[4 * q] + b.y * wn[4 * q + 1] + b.z * wn[4 * q + 2] + b.w * wn[4 * q + 3];
    }
    sh1[nl * HID_F + j] = fmaxf(acc, 0.0f);
  }
  __syncthreads();

  // ---- phase 2: half-wave (32 lanes) per node; lanes 0-15 t2, 16-31 s2 ----
  int oc = t & 31;
  int c = oc & 15;
  const float* W2 = (oc < 16) ? W2n : W2s;
  float w2[HID_F];
#pragma unroll
  for (int k = 0; k < HID_F; ++k) w2[k] = W2[k * OUT_F + c];

  int hw = t >> 5;  // half-wave id 0..7
#pragma unroll 2
  for (int i = 0; i < 8; ++i) {
    int nl = hw * 8 + i;
    int v = tile + nl;
    if (nl < nvalid) {
      const float4* h4 = (const float4*)(sh1 + nl * HID_F);
      float acc = 0.0f;
#pragma unroll
      for (int q = 0; q < 16; ++q) {
        float4 a = h4[q];
        acc += a.x * w2[4 * q] + a.y * w2[4 * q + 1] + a.z * w2[4 * q + 2] + a.w * w2[4 * q + 3];
      }
      if (oc < 16) t2[v * OUT_F + c] = acc;
      else         s2[v * OUT_F + c] = acc;
    }
  }
}

// ---------------- layer 2 aggregate + final: float4, 4 lanes/node ----------------
__global__ __launch_bounds__(256) void gather2_final_kernel(
    const int* __restrict__ ptr, const int* __restrict__ col,
    const float* __restrict__ t2, const float* __restrict__ s2,
    const float* __restrict__ b2, float* __restrict__ out) {
  int gid = blockIdx.x * 256 + threadIdx.x;
  int v = gid >> 2;
  int c4 = gid & 3;
  if (v >= N_NODES) return;
  int start = (v == 0) ? 0 : ptr[v - 1];
  int end = ptr[v];
  const float4* T = (const float4*)t2;
  float4 a0 = {0.f, 0.f, 0.f, 0.f}, a1 = {0.f, 0.f, 0.f, 0.f};
  int e = start;
  for (; e + 1 < end; e += 2) {
    int c0 = col[e], c1 = col[e + 1];
    float4 x = T[c0 * 4 + c4];
    float4 y = T[c1 * 4 + c4];
    a0.x += x.x; a0.y += x.y; a0.z += x.z; a0.w += x.w;
    a1.x += y.x; a1.y += y.y; a1.z += y.z; a1.w += y.w;
  }
  if (e < end) {
    float4 x = T[col[e] * 4 + c4];
    a0.x += x.x; a0.y += x.y; a0.z += x.z; a0.w += x.w;
  }
  float inv = 1.0f / fmaxf((float)(end - start), 1.0f);
  float4 sv = ((const float4*)s2)[v * 4 + c4];
  float4 bv = ((const float4*)b2)[c4];
  float4 r;
  r.x = sv.x + bv.x + (a0.x + a1.x) * inv;
  r.y = sv.y + bv.y + (a0.y + a1.y) * inv;
  r.z = sv.z + bv.z + (a0.z + a1.z) * inv;
  r.w = sv.w + bv.w + (a0.w + a1.w) * inv;
  ((float4*)out)[v * 4 + c4] = r;
}

extern "C" void kernel_launch(void* const* d_in, const int* in_sizes, int n_in,
                              void* d_out, int out_size, void* d_ws, size_t ws_size,
                              hipStream_t stream) {
  const float* feat = (const float*)d_in[0];
  const int* src    = (const int*)d_in[1];
  const int* dst    = (const int*)d_in[2];
  const float* W1s  = (const float*)d_in[3];
  const float* W1n  = (const float*)d_in[4];
  const float* b1   = (const float*)d_in[5];
  const float* W2s  = (const float*)d_in[6];
  const float* W2n  = (const float*)d_in[7];
  const float* b2   = (const float*)d_in[8];
  float* out = (float*)d_out;

  const int N = N_NODES;
  // workspace layout (~33 MB). sorted[] aliases meanf[] (consumed before gather1).
  int* cnt = (int*)d_ws;                    // N
  int* ptr = cnt + N;                       // N (+8 pad)
  int* col = ptr + N + 8;                   // E
  float* meanf = (float*)(col + N_EDGES);   // 32N floats
  uint2* sorted = (uint2*)meanf;            // E pairs (12.8MB) — fits in 32N floats
  float* t2 = meanf + 32 * (size_t)N;       // 16N
  float* s2 = t2 + 16 * (size_t)N;          // 16N
  int* bsum = (int*)(s2 + 16 * (size_t)N);  // 512
  int* bscan = bsum + 512;                  // 512
  int* cursor = bscan + 512;                // 128

  hipMemsetAsync(cnt, 0, N * sizeof(int), stream);

  count_kernel<<<(N_EDGES + 255) / 256, 256, 0, stream>>>(dst, cnt);
  scan1_kernel<<<NB, 256, 0, stream>>>(cnt, bsum);
  scan2_kernel<<<1, 512, 0, stream>>>(bsum, bscan);
  scan3_kernel<<<NB, 256, 0, stream>>>(cnt, bscan, ptr);
  cursor_init_kernel<<<1, 128, 0, stream>>>(ptr, cursor);
  bucket_kernel<<<(N_EDGES + CHUNK - 1) / CHUNK, 256, 0, stream>>>(src, dst, cursor, sorted);
  fill2_kernel<<<(N_EDGES + 255) / 256, 256, 0, stream>>>(sorted, ptr, col);

  gather1_kernel<<<N * 8 / 256, 256, 0, stream>>>(ptr, col, feat, meanf);
  l1t2s2_kernel<<<(N + 63) / 64, 256, 0, stream>>>(feat, meanf, W1s, W1n, b1,
                                                   W2n, W2s, t2, s2);
  gather2_final_kernel<<<(N * 4 + 255) / 256, 256, 0, stream>>>(ptr, col, t2, s2,
                                                                b2, out);
}

// Round 6
// 248.317 us; speedup vs baseline: 2.0874x; 1.3576x over previous
//
#include <hip/hip_runtime.h>

#define N_NODES 100000
#define N_EDGES 1600000
#define IN_F 32
#define HID_F 64
#define OUT_F 16
#define NBKT 128                     // buckets (98 used), bucket = dst >> 10
#define BSIZE 1024                   // nodes per bucket
#define CHUNK 4096                   // edges per block in bucket-sort pass
#define NBLK_CSR ((N_NODES + BSIZE - 1) / BSIZE)   // 98

// ---------------- bucket histogram: LDS hist + 128 global atomics/block ----------------
__global__ __launch_bounds__(256) void bhist_kernel(
    const int* __restrict__ dst, int* __restrict__ bhist) {
  __shared__ int h[NBKT];
  for (int i = threadIdx.x; i < NBKT; i += 256) h[i] = 0;
  __syncthreads();
  int base = blockIdx.x * CHUNK;
  int lim = min(CHUNK, N_EDGES - base);
  for (int i = threadIdx.x; i < lim; i += 256)
    atomicAdd(&h[dst[base + i] >> 10], 1);
  __syncthreads();
  if (threadIdx.x < NBKT && h[threadIdx.x])
    atomicAdd(&bhist[threadIdx.x], h[threadIdx.x]);
}

// ---------------- scan of 128 bucket counts -> bbase (incl-end), bcursor (excl) ----------------
__global__ __launch_bounds__(128) void bscan_kernel(
    const int* __restrict__ bhist, int* __restrict__ bbase,
    int* __restrict__ bcursor) {
  __shared__ int sh[NBKT];
  int t = threadIdx.x;
  int v = bhist[t];
  sh[t] = v;
  __syncthreads();
  for (int off = 1; off < NBKT; off <<= 1) {
    int u = (t >= off) ? sh[t - off] : 0;
    __syncthreads();
    sh[t] += u;
    __syncthreads();
  }
  bbase[t + 1] = sh[t];
  if (t == 0) bbase[0] = 0;
  bcursor[t] = sh[t] - v;  // exclusive base
}

// ---------------- one-pass LDS-staged bucket sort of edges by dst>>10 ----------------
__global__ __launch_bounds__(256) void bucket_kernel(
    const int* __restrict__ src, const int* __restrict__ dst,
    int* __restrict__ cursor, uint2* __restrict__ sorted) {
  __shared__ uint2 stage[CHUNK];         // 32 KB
  __shared__ int lcnt[NBKT], lscan[NBKT], gbase[NBKT];
  int t = threadIdx.x;
  for (int i = t; i < NBKT; i += 256) lcnt[i] = 0;
  __syncthreads();

  int base = blockIdx.x * CHUNK;
  uint2 mypair[CHUNK / 256];
  int myb[CHUNK / 256], myrank[CHUNK / 256];
#pragma unroll
  for (int i = 0; i < CHUNK / 256; ++i) {
    int e = base + t + 256 * i;
    if (e < N_EDGES) {
      int s = src[e], d = dst[e];
      mypair[i].x = (unsigned)s;
      mypair[i].y = (unsigned)d;
      myb[i] = d >> 10;
      myrank[i] = atomicAdd(&lcnt[myb[i]], 1);
    } else {
      myb[i] = -1;
    }
  }
  __syncthreads();
  if (t < NBKT) lscan[t] = lcnt[t];
  __syncthreads();
  for (int off = 1; off < NBKT; off <<= 1) {
    int v = (t < NBKT && t >= off) ? lscan[t - off] : 0;
    __syncthreads();
    if (t < NBKT) lscan[t] += v;
    __syncthreads();
  }
  if (t < NBKT) gbase[t] = lcnt[t] ? atomicAdd(&cursor[t], lcnt[t]) : 0;
  __syncthreads();
#pragma unroll
  for (int i = 0; i < CHUNK / 256; ++i) {
    if (myb[i] >= 0) {
      int slot = (lscan[myb[i]] - lcnt[myb[i]]) + myrank[i];
      stage[slot] = mypair[i];
    }
  }
  __syncthreads();
  int nvalid = min(CHUNK, N_EDGES - base);
  for (int i = t; i < nvalid; i += 256) {
    uint2 p = stage[i];
    int b = (int)(p.y >> 10);
    int addr = gbase[b] + (i - (lscan[b] - lcnt[b]));
    sorted[addr] = p;
  }
}

// ---------------- per-bucket exact CSR build, all in LDS (no global atomics) ----------------
// ptr[v] = global inclusive end offset; col filled per-bucket.
__global__ __launch_bounds__(512) void bcsr_kernel(
    const uint2* __restrict__ sorted, const int* __restrict__ bbase,
    int* __restrict__ ptr, int* __restrict__ col) {
  __shared__ int lcnt[BSIZE];   // 4 KB
  __shared__ int lcur[BSIZE];   // 4 KB
  __shared__ int part[512];     // 2 KB
  int t = threadIdx.x;
  int b = blockIdx.x;
  int base = bbase[b];
  int ne = bbase[b + 1] - base;

  lcnt[t] = 0;
  lcnt[t + 512] = 0;
  __syncthreads();
  for (int i = t; i < ne; i += 512)
    atomicAdd(&lcnt[sorted[base + i].y & (BSIZE - 1)], 1);
  __syncthreads();

  // scan: thread t owns local nodes 2t, 2t+1
  int c0 = lcnt[2 * t], c1 = lcnt[2 * t + 1];
  int s = c0 + c1;
  part[t] = s;
  __syncthreads();
  for (int off = 1; off < 512; off <<= 1) {
    int u = (t >= off) ? part[t - off] : 0;
    __syncthreads();
    part[t] += u;
    __syncthreads();
  }
  int excl = part[t] - s;
  lcur[2 * t] = base + excl;          // start cursors
  lcur[2 * t + 1] = base + excl + c0;
  int v0 = b * BSIZE + 2 * t;
  if (v0 < N_NODES) ptr[v0] = base + excl + c0;          // inclusive end
  if (v0 + 1 < N_NODES) ptr[v0 + 1] = base + excl + s;
  __syncthreads();

  for (int i = t; i < ne; i += 512) {
    uint2 p = sorted[base + i];
    int pos = atomicAdd(&lcur[p.y & (BSIZE - 1)], 1);
    col[pos] = (int)p.x;
  }
}

// ---------------- layer 1 aggregate: float4 gather, 8 lanes/node ----------------
__global__ __launch_bounds__(256) void gather1_kernel(
    const int* __restrict__ ptr, const int* __restrict__ col,
    const float* __restrict__ feat, float* __restrict__ meanf) {
  int gid = blockIdx.x * 256 + threadIdx.x;
  int v = gid >> 3;
  int f4 = gid & 7;
  int start = (v == 0) ? 0 : ptr[v - 1];
  int end = ptr[v];
  const float4* F = (const float4*)feat;
  float4 s0 = {0.f, 0.f, 0.f, 0.f}, s1 = {0.f, 0.f, 0.f, 0.f};
  int e = start;
  for (; e + 1 < end; e += 2) {
    int c0 = col[e], c1 = col[e + 1];
    float4 a = F[c0 * 8 + f4];
    float4 b = F[c1 * 8 + f4];
    s0.x += a.x; s0.y += a.y; s0.z += a.z; s0.w += a.w;
    s1.x += b.x; s1.y += b.y; s1.z += b.z; s1.w += b.w;
  }
  if (e < end) {
    float4 a = F[col[e] * 8 + f4];
    s0.x += a.x; s0.y += a.y; s0.z += a.z; s0.w += a.w;
  }
  float inv = 1.0f / fmaxf((float)(end - start), 1.0f);
  float4 r;
  r.x = (s0.x + s1.x) * inv; r.y = (s0.y + s1.y) * inv;
  r.z = (s0.z + s1.z) * inv; r.w = (s0.w + s1.w) * inv;
  ((float4*)meanf)[v * 8 + f4] = r;
}

// ------- fused: h1 = relu(feat@W1s + meanf@W1n + b1) in LDS; t2=h1@W2n, s2=h1@W2s -------
__global__ __launch_bounds__(256) void l1t2s2_kernel(
    const float* __restrict__ feat, const float* __restrict__ meanf,
    const float* __restrict__ W1s, const float* __restrict__ W1n,
    const float* __restrict__ b1,
    const float* __restrict__ W2n, const float* __restrict__ W2s,
    float* __restrict__ t2, float* __restrict__ s2) {
  __shared__ float sfeat[64 * IN_F];   // 8 KB
  __shared__ float smean[64 * IN_F];   // 8 KB
  __shared__ float sh1[64 * HID_F];    // 16 KB

  int t = threadIdx.x;
  int tile = blockIdx.x * 64;
  int nvalid = min(64, N_NODES - tile);

  {
    const float4* Fg = (const float4*)(feat + (size_t)tile * IN_F);
    const float4* Mg = (const float4*)(meanf + (size_t)tile * IN_F);
    float4* Fs = (float4*)sfeat;
    float4* Ms = (float4*)smean;
    int lim = nvalid * 8;
#pragma unroll
    for (int i = 0; i < 2; ++i) {
      int idx = t + 256 * i;
      if (idx < lim) { Fs[idx] = Fg[idx]; Ms[idx] = Mg[idx]; }
    }
  }

  int j = t & 63;
  float ws[IN_F], wn[IN_F];
#pragma unroll
  for (int k = 0; k < IN_F; ++k) {
    ws[k] = W1s[k * HID_F + j];
    wn[k] = W1n[k * HID_F + j];
  }
  float bj = b1[j];
  __syncthreads();

  int wv = t >> 6;
#pragma unroll 2
  for (int i = 0; i < 16; ++i) {
    int nl = wv * 16 + i;
    const float4* f4 = (const float4*)(sfeat + nl * IN_F);
    const float4* m4 = (const float4*)(smean + nl * IN_F);
    float acc = bj;
#pragma unroll
    for (int q = 0; q < 8; ++q) {
      float4 a = f4[q];
      float4 b = m4[q];
      acc += a.x * ws[4 * q] + a.y * ws[4 * q + 1] + a.z * ws[4 * q + 2] + a.w * ws[4 * q + 3];
      acc += b.x * wn[4 * q] + b.y * wn[4 * q + 1] + b.z * wn[4 * q + 2] + b.w * wn[4 * q + 3];
    }
    sh1[nl * HID_F + j] = fmaxf(acc, 0.0f);
  }
  __syncthreads();

  int oc = t & 31;
  int c = oc & 15;
  const float* W2 = (oc < 16) ? W2n : W2s;
  float w2[HID_F];
#pragma unroll
  for (int k = 0; k < HID_F; ++k) w2[k] = W2[k * OUT_F + c];

  int hw = t >> 5;
#pragma unroll 2
  for (int i = 0; i < 8; ++i) {
    int nl = hw * 8 + i;
    int v = tile + nl;
    if (nl < nvalid) {
      const float4* h4 = (const float4*)(sh1 + nl * HID_F);
      float acc = 0.0f;
#pragma unroll
      for (int q = 0; q < 16; ++q) {
        float4 a = h4[q];
        acc += a.x * w2[4 * q] + a.y * w2[4 * q + 1] + a.z * w2[4 * q + 2] + a.w * w2[4 * q + 3];
      }
      if (oc < 16) t2[v * OUT_F + c] = acc;
      else         s2[v * OUT_F + c] = acc;
    }
  }
}

// ---------------- layer 2 aggregate + final: float4, 4 lanes/node ----------------
__global__ __launch_bounds__(256) void gather2_final_kernel(
    const int* __restrict__ ptr, const int* __restrict__ col,
    const float* __restrict__ t2, const float* __restrict__ s2,
    const float* __restrict__ b2, float* __restrict__ out) {
  int gid = blockIdx.x * 256 + threadIdx.x;
  int v = gid >> 2;
  int c4 = gid & 3;
  if (v >= N_NODES) return;
  int start = (v == 0) ? 0 : ptr[v - 1];
  int end = ptr[v];
  const float4* T = (const float4*)t2;
  float4 a0 = {0.f, 0.f, 0.f, 0.f}, a1 = {0.f, 0.f, 0.f, 0.f};
  int e = start;
  for (; e + 1 < end; e += 2) {
    int c0 = col[e], c1 = col[e + 1];
    float4 x = T[c0 * 4 + c4];
    float4 y = T[c1 * 4 + c4];
    a0.x += x.x; a0.y += x.y; a0.z += x.z; a0.w += x.w;
    a1.x += y.x; a1.y += y.y; a1.z += y.z; a1.w += y.w;
  }
  if (e < end) {
    float4 x = T[col[e] * 4 + c4];
    a0.x += x.x; a0.y += x.y; a0.z += x.z; a0.w += x.w;
  }
  float inv = 1.0f / fmaxf((float)(end - start), 1.0f);
  float4 sv = ((const float4*)s2)[v * 4 + c4];
  float4 bv = ((const float4*)b2)[c4];
  float4 r;
  r.x = sv.x + bv.x + (a0.x + a1.x) * inv;
  r.y = sv.y + bv.y + (a0.y + a1.y) * inv;
  r.z = sv.z + bv.z + (a0.z + a1.z) * inv;
  r.w = sv.w + bv.w + (a0.w + a1.w) * inv;
  ((float4*)out)[v * 4 + c4] = r;
}

extern "C" void kernel_launch(void* const* d_in, const int* in_sizes, int n_in,
                              void* d_out, int out_size, void* d_ws, size_t ws_size,
                              hipStream_t stream) {
  const float* feat = (const float*)d_in[0];
  const int* src    = (const int*)d_in[1];
  const int* dst    = (const int*)d_in[2];
  const float* W1s  = (const float*)d_in[3];
  const float* W1n  = (const float*)d_in[4];
  const float* b1   = (const float*)d_in[5];
  const float* W2s  = (const float*)d_in[6];
  const float* W2n  = (const float*)d_in[7];
  const float* b2   = (const float*)d_in[8];
  float* out = (float*)d_out;

  const int N = N_NODES;
  // workspace layout (~33 MB). sorted[] aliases meanf[] (consumed by bcsr before gather1).
  int* ptr = (int*)d_ws;                    // N (+8 pad)
  int* col = ptr + N + 8;                   // E
  float* meanf = (float*)(col + N_EDGES);   // 32N floats
  uint2* sorted = (uint2*)meanf;            // E pairs (12.8MB) — fits in 32N floats
  float* t2 = meanf + 32 * (size_t)N;       // 16N
  float* s2 = t2 + 16 * (size_t)N;          // 16N
  int* bhist = (int*)(s2 + 16 * (size_t)N); // 128
  int* bbase = bhist + NBKT;                // 129 (+pad)
  int* bcursor = bbase + NBKT + 8;          // 128

  hipMemsetAsync(bhist, 0, NBKT * sizeof(int), stream);

  bhist_kernel<<<(N_EDGES + CHUNK - 1) / CHUNK, 256, 0, stream>>>(dst, bhist);
  bscan_kernel<<<1, NBKT, 0, stream>>>(bhist, bbase, bcursor);
  bucket_kernel<<<(N_EDGES + CHUNK - 1) / CHUNK, 256, 0, stream>>>(src, dst, bcursor, sorted);
  bcsr_kernel<<<NBLK_CSR, 512, 0, stream>>>(sorted, bbase, ptr, col);

  gather1_kernel<<<N * 8 / 256, 256, 0, stream>>>(ptr, col, feat, meanf);
  l1t2s2_kernel<<<(N + 63) / 64, 256, 0, stream>>>(feat, meanf, W1s, W1n, b1,
                                                   W2n, W2s, t2, s2);
  gather2_final_kernel<<<(N * 4 + 255) / 256, 256, 0, stream>>>(ptr, col, t2, s2,
                                                                b2, out);
}

// Round 7
// 227.965 us; speedup vs baseline: 2.2738x; 1.0893x over previous
//
#include <hip/hip_runtime.h>

#define N_NODES 100000
#define N_EDGES 1600000
#define IN_F 32
#define HID_F 64
#define OUT_F 16
#define NBKT 128                     // buckets (98 used), bucket = dst >> 10
#define BSIZE 1024                   // nodes per bucket
#define CHUNK 4096                   // edges per block in bucket-sort pass
#define NBLK_CSR ((N_NODES + BSIZE - 1) / BSIZE)   // 98
#define APITCH 68                    // padded pitch for transposed A / h1 tiles

// ---------------- bucket histogram: LDS hist + 128 global atomics/block ----------------
__global__ __launch_bounds__(256) void bhist_kernel(
    const int* __restrict__ dst, int* __restrict__ bhist) {
  __shared__ int h[NBKT];
  for (int i = threadIdx.x; i < NBKT; i += 256) h[i] = 0;
  __syncthreads();
  int base = blockIdx.x * CHUNK;
  int lim = min(CHUNK, N_EDGES - base);
  for (int i = threadIdx.x; i < lim; i += 256)
    atomicAdd(&h[dst[base + i] >> 10], 1);
  __syncthreads();
  if (threadIdx.x < NBKT && h[threadIdx.x])
    atomicAdd(&bhist[threadIdx.x], h[threadIdx.x]);
}

// ---------------- scan of 128 bucket counts -> bbase (incl-end), bcursor (excl) ----------------
__global__ __launch_bounds__(128) void bscan_kernel(
    const int* __restrict__ bhist, int* __restrict__ bbase,
    int* __restrict__ bcursor) {
  __shared__ int sh[NBKT];
  int t = threadIdx.x;
  int v = bhist[t];
  sh[t] = v;
  __syncthreads();
  for (int off = 1; off < NBKT; off <<= 1) {
    int u = (t >= off) ? sh[t - off] : 0;
    __syncthreads();
    sh[t] += u;
    __syncthreads();
  }
  bbase[t + 1] = sh[t];
  if (t == 0) bbase[0] = 0;
  bcursor[t] = sh[t] - v;  // exclusive base
}

// ---------------- one-pass LDS-staged bucket sort of edges by dst>>10 ----------------
__global__ __launch_bounds__(256) void bucket_kernel(
    const int* __restrict__ src, const int* __restrict__ dst,
    int* __restrict__ cursor, uint2* __restrict__ sorted) {
  __shared__ uint2 stage[CHUNK];         // 32 KB
  __shared__ int lcnt[NBKT], lscan[NBKT], gbase[NBKT];
  int t = threadIdx.x;
  for (int i = t; i < NBKT; i += 256) lcnt[i] = 0;
  __syncthreads();

  int base = blockIdx.x * CHUNK;
  uint2 mypair[CHUNK / 256];
  int myb[CHUNK / 256], myrank[CHUNK / 256];
#pragma unroll
  for (int i = 0; i < CHUNK / 256; ++i) {
    int e = base + t + 256 * i;
    if (e < N_EDGES) {
      int s = src[e], d = dst[e];
      mypair[i].x = (unsigned)s;
      mypair[i].y = (unsigned)d;
      myb[i] = d >> 10;
      myrank[i] = atomicAdd(&lcnt[myb[i]], 1);
    } else {
      myb[i] = -1;
    }
  }
  __syncthreads();
  if (t < NBKT) lscan[t] = lcnt[t];
  __syncthreads();
  for (int off = 1; off < NBKT; off <<= 1) {
    int v = (t < NBKT && t >= off) ? lscan[t - off] : 0;
    __syncthreads();
    if (t < NBKT) lscan[t] += v;
    __syncthreads();
  }
  if (t < NBKT) gbase[t] = lcnt[t] ? atomicAdd(&cursor[t], lcnt[t]) : 0;
  __syncthreads();
#pragma unroll
  for (int i = 0; i < CHUNK / 256; ++i) {
    if (myb[i] >= 0) {
      int slot = (lscan[myb[i]] - lcnt[myb[i]]) + myrank[i];
      stage[slot] = mypair[i];
    }
  }
  __syncthreads();
  int nvalid = min(CHUNK, N_EDGES - base);
  for (int i = t; i < nvalid; i += 256) {
    uint2 p = stage[i];
    int b = (int)(p.y >> 10);
    int addr = gbase[b] + (i - (lscan[b] - lcnt[b]));
    sorted[addr] = p;
  }
}

// ---------------- per-bucket exact CSR build, all in LDS (no global atomics) ----------------
__global__ __launch_bounds__(512) void bcsr_kernel(
    const uint2* __restrict__ sorted, const int* __restrict__ bbase,
    int* __restrict__ ptr, int* __restrict__ col) {
  __shared__ int lcnt[BSIZE];   // 4 KB
  __shared__ int lcur[BSIZE];   // 4 KB
  __shared__ int part[512];     // 2 KB
  int t = threadIdx.x;
  int b = blockIdx.x;
  int base = bbase[b];
  int ne = bbase[b + 1] - base;

  lcnt[t] = 0;
  lcnt[t + 512] = 0;
  __syncthreads();
  for (int i = t; i < ne; i += 512)
    atomicAdd(&lcnt[sorted[base + i].y & (BSIZE - 1)], 1);
  __syncthreads();

  int c0 = lcnt[2 * t], c1 = lcnt[2 * t + 1];
  int s = c0 + c1;
  part[t] = s;
  __syncthreads();
  for (int off = 1; off < 512; off <<= 1) {
    int u = (t >= off) ? part[t - off] : 0;
    __syncthreads();
    part[t] += u;
    __syncthreads();
  }
  int excl = part[t] - s;
  lcur[2 * t] = base + excl;
  lcur[2 * t + 1] = base + excl + c0;
  int v0 = b * BSIZE + 2 * t;
  if (v0 < N_NODES) ptr[v0] = base + excl + c0;
  if (v0 + 1 < N_NODES) ptr[v0 + 1] = base + excl + s;
  __syncthreads();

  for (int i = t; i < ne; i += 512) {
    uint2 p = sorted[base + i];
    int pos = atomicAdd(&lcur[p.y & (BSIZE - 1)], 1);
    col[pos] = (int)p.x;
  }
}

// ---------------- layer 1 aggregate: float4 gather, 8 lanes/node ----------------
__global__ __launch_bounds__(256) void gather1_kernel(
    const int* __restrict__ ptr, const int* __restrict__ col,
    const float* __restrict__ feat, float* __restrict__ meanf) {
  int gid = blockIdx.x * 256 + threadIdx.x;
  int v = gid >> 3;
  int f4 = gid & 7;
  int start = (v == 0) ? 0 : ptr[v - 1];
  int end = ptr[v];
  const float4* F = (const float4*)feat;
  float4 s0 = {0.f, 0.f, 0.f, 0.f}, s1 = {0.f, 0.f, 0.f, 0.f};
  int e = start;
  for (; e + 1 < end; e += 2) {
    int c0 = col[e], c1 = col[e + 1];
    float4 a = F[c0 * 8 + f4];
    float4 b = F[c1 * 8 + f4];
    s0.x += a.x; s0.y += a.y; s0.z += a.z; s0.w += a.w;
    s1.x += b.x; s1.y += b.y; s1.z += b.z; s1.w += b.w;
  }
  if (e < end) {
    float4 a = F[col[e] * 8 + f4];
    s0.x += a.x; s0.y += a.y; s0.z += a.z; s0.w += a.w;
  }
  float inv = 1.0f / fmaxf((float)(end - start), 1.0f);
  float4 r;
  r.x = (s0.x + s1.x) * inv; r.y = (s0.y + s1.y) * inv;
  r.z = (s0.z + s1.z) * inv; r.w = (s0.w + s1.w) * inv;
  ((float4*)meanf)[v * 8 + f4] = r;
}

// ------- fused register-tiled GEMM: h1 = relu([feat|meanf] @ [W1s;W1n] + b1);
//         t2 = h1 @ W2n, s2 = h1 @ W2s. 4x4 tile/thread phase 1, 4x2 phase 2. -------
__global__ __launch_bounds__(256) void l1t2s2_kernel(
    const float* __restrict__ feat, const float* __restrict__ meanf,
    const float* __restrict__ W1s, const float* __restrict__ W1n,
    const float* __restrict__ b1,
    const float* __restrict__ W2n, const float* __restrict__ W2s,
    float* __restrict__ t2, float* __restrict__ s2) {
  __shared__ float sA[64 * APITCH];   // A^T: sA[k][n], k=0..63 (feat|meanf), 17 KB
  __shared__ float sW[64 * 64];       // W: sW[k][c], 16 KB; phase 2 reuses as [64][32]

  int t = threadIdx.x;
  int tile = blockIdx.x * 64;
  int nvalid = min(64, N_NODES - tile);

  // ---- stage A^T (transposed scalar writes; coalesced float4 global reads) ----
  {
    const float4* Fg = (const float4*)(feat + (size_t)tile * IN_F);
    const float4* Mg = (const float4*)(meanf + (size_t)tile * IN_F);
    int lim = nvalid * 8;
#pragma unroll
    for (int it = 0; it < 2; ++it) {
      int idx = t + 256 * it;
      int n = idx >> 3, c = idx & 7;
      if (idx < lim) {
        float4 a = Fg[idx];
        sA[(4 * c + 0) * APITCH + n] = a.x;
        sA[(4 * c + 1) * APITCH + n] = a.y;
        sA[(4 * c + 2) * APITCH + n] = a.z;
        sA[(4 * c + 3) * APITCH + n] = a.w;
        float4 m = Mg[idx];
        sA[(32 + 4 * c + 0) * APITCH + n] = m.x;
        sA[(32 + 4 * c + 1) * APITCH + n] = m.y;
        sA[(32 + 4 * c + 2) * APITCH + n] = m.z;
        sA[(32 + 4 * c + 3) * APITCH + n] = m.w;
      }
    }
  }
  // ---- stage W = [W1s ; W1n] (row-major, coalesced f4) ----
  {
    float4* Ws = (float4*)sW;
#pragma unroll
    for (int it = 0; it < 4; ++it) {
      int idx = t + 256 * it;          // 0..1023, row = idx>>4, chunk = idx&15
      int row = idx >> 4;
      const float4* srcw = (row < 32) ? (const float4*)W1s : (const float4*)W1n;
      Ws[idx] = srcw[(row & 31) * 16 + (idx & 15)];
    }
  }
  int tx = t & 15, ty = t >> 4;
  int n0 = 4 * ty, c0 = 4 * tx;
  float4 bb = ((const float4*)b1)[tx];
  __syncthreads();

  // ---- phase 1: 4x4 register tile, 2 ds_read_b128 -> 16 FMA per k ----
  float acc[4][4];
#pragma unroll
  for (int i = 0; i < 4; ++i) { acc[i][0] = bb.x; acc[i][1] = bb.y; acc[i][2] = bb.z; acc[i][3] = bb.w; }
#pragma unroll 4
  for (int k = 0; k < 64; ++k) {
    float4 a = *(const float4*)&sA[k * APITCH + n0];
    float4 w = *(const float4*)&sW[k * 64 + c0];
    acc[0][0] += a.x * w.x; acc[0][1] += a.x * w.y; acc[0][2] += a.x * w.z; acc[0][3] += a.x * w.w;
    acc[1][0] += a.y * w.x; acc[1][1] += a.y * w.y; acc[1][2] += a.y * w.z; acc[1][3] += a.y * w.w;
    acc[2][0] += a.z * w.x; acc[2][1] += a.z * w.y; acc[2][2] += a.z * w.z; acc[2][3] += a.z * w.w;
    acc[3][0] += a.w * w.x; acc[3][1] += a.w * w.y; acc[3][2] += a.w * w.z; acc[3][3] += a.w * w.w;
  }
  __syncthreads();   // all reads of sA/sW done

  // ---- write h1^T (relu) into sA region; restage W2cat=[W2n|W2s] into sW ----
#pragma unroll
  for (int jj = 0; jj < 4; ++jj) {
    float4 v;
    v.x = fmaxf(acc[0][jj], 0.0f);
    v.y = fmaxf(acc[1][jj], 0.0f);
    v.z = fmaxf(acc[2][jj], 0.0f);
    v.w = fmaxf(acc[3][jj], 0.0f);
    *(float4*)&sA[(c0 + jj) * APITCH + n0] = v;   // sh1T[j][n]
  }
  {
    float4* Ws = (float4*)sW;                     // phase-2 pitch: 32 floats = 8 f4
#pragma unroll
    for (int it = 0; it < 2; ++it) {
      int idx = t + 256 * it;                     // 0..511, row = idx>>3, ch = idx&7
      int row = idx >> 3, ch = idx & 7;
      const float4* srcw = (ch < 4) ? (const float4*)W2n : (const float4*)W2s;
      Ws[row * 8 + ch] = srcw[row * 4 + (ch & 3)];
    }
  }
  __syncthreads();

  // ---- phase 2: 4 nodes x 2 cols per thread; 2 ds reads -> 8 FMA per k ----
  int c2 = 2 * tx;   // 0..30; <16 -> t2 col, >=16 -> s2 col (c2-16)
  float a0 = 0.f, a1 = 0.f, b0 = 0.f, b1_ = 0.f, d0 = 0.f, d1 = 0.f, e0 = 0.f, e1 = 0.f;
#pragma unroll 4
  for (int k = 0; k < 64; ++k) {
    float4 a = *(const float4*)&sA[k * APITCH + n0];
    float2 w = *(const float2*)&sW[k * 32 + c2];
    a0 += a.x * w.x; a1 += a.x * w.y;
    b0 += a.y * w.x; b1_ += a.y * w.y;
    d0 += a.z * w.x; d1 += a.z * w.y;
    e0 += a.w * w.x; e1 += a.w * w.y;
  }
  {
    float rs[4][2] = {{a0, a1}, {b0, b1_}, {d0, d1}, {e0, e1}};
    float* outp = (c2 < 16) ? t2 : s2;
    int cc = c2 & 15;
#pragma unroll
    for (int i = 0; i < 4; ++i) {
      int v = tile + n0 + i;
      if (v < N_NODES) *(float2*)&outp[v * OUT_F + cc] = make_float2(rs[i][0], rs[i][1]);
    }
  }
}

// ---------------- layer 2 aggregate + final: float4, 4 lanes/node ----------------
__global__ __launch_bounds__(256) void gather2_final_kernel(
    const int* __restrict__ ptr, const int* __restrict__ col,
    const float* __restrict__ t2, const float* __restrict__ s2,
    const float* __restrict__ b2, float* __restrict__ out) {
  int gid = blockIdx.x * 256 + threadIdx.x;
  int v = gid >> 2;
  int c4 = gid & 3;
  if (v >= N_NODES) return;
  int start = (v == 0) ? 0 : ptr[v - 1];
  int end = ptr[v];
  const float4* T = (const float4*)t2;
  float4 a0 = {0.f, 0.f, 0.f, 0.f}, a1 = {0.f, 0.f, 0.f, 0.f};
  int e = start;
  for (; e + 1 < end; e += 2) {
    int c0 = col[e], c1 = col[e + 1];
    float4 x = T[c0 * 4 + c4];
    float4 y = T[c1 * 4 + c4];
    a0.x += x.x; a0.y += x.y; a0.z += x.z; a0.w += x.w;
    a1.x += y.x; a1.y += y.y; a1.z += y.z; a1.w += y.w;
  }
  if (e < end) {
    float4 x = T[col[e] * 4 + c4];
    a0.x += x.x; a0.y += x.y; a0.z += x.z; a0.w += x.w;
  }
  float inv = 1.0f / fmaxf((float)(end - start), 1.0f);
  float4 sv = ((const float4*)s2)[v * 4 + c4];
  float4 bv = ((const float4*)b2)[c4];
  float4 r;
  r.x = sv.x + bv.x + (a0.x + a1.x) * inv;
  r.y = sv.y + bv.y + (a0.y + a1.y) * inv;
  r.z = sv.z + bv.z + (a0.z + a1.z) * inv;
  r.w = sv.w + bv.w + (a0.w + a1.w) * inv;
  ((float4*)out)[v * 4 + c4] = r;
}

extern "C" void kernel_launch(void* const* d_in, const int* in_sizes, int n_in,
                              void* d_out, int out_size, void* d_ws, size_t ws_size,
                              hipStream_t stream) {
  const float* feat = (const float*)d_in[0];
  const int* src    = (const int*)d_in[1];
  const int* dst    = (const int*)d_in[2];
  const float* W1s  = (const float*)d_in[3];
  const float* W1n  = (const float*)d_in[4];
  const float* b1   = (const float*)d_in[5];
  const float* W2s  = (const float*)d_in[6];
  const float* W2n  = (const float*)d_in[7];
  const float* b2   = (const float*)d_in[8];
  float* out = (float*)d_out;

  const int N = N_NODES;
  // workspace layout (~33 MB). sorted[] aliases meanf[] (consumed by bcsr before gather1).
  int* ptr = (int*)d_ws;                    // N (+8 pad)
  int* col = ptr + N + 8;                   // E
  float* meanf = (float*)(col + N_EDGES);   // 32N floats
  uint2* sorted = (uint2*)meanf;            // E pairs (12.8MB) — fits in 32N floats
  float* t2 = meanf + 32 * (size_t)N;       // 16N
  float* s2 = t2 + 16 * (size_t)N;          // 16N
  int* bhist = (int*)(s2 + 16 * (size_t)N); // 128
  int* bbase = bhist + NBKT;                // 129 (+pad)
  int* bcursor = bbase + NBKT + 8;          // 128

  hipMemsetAsync(bhist, 0, NBKT * sizeof(int), stream);

  bhist_kernel<<<(N_EDGES + CHUNK - 1) / CHUNK, 256, 0, stream>>>(dst, bhist);
  bscan_kernel<<<1, NBKT, 0, stream>>>(bhist, bbase, bcursor);
  bucket_kernel<<<(N_EDGES + CHUNK - 1) / CHUNK, 256, 0, stream>>>(src, dst, bcursor, sorted);
  bcsr_kernel<<<NBLK_CSR, 512, 0, stream>>>(sorted, bbase, ptr, col);

  gather1_kernel<<<N * 8 / 256, 256, 0, stream>>>(ptr, col, feat, meanf);
  l1t2s2_kernel<<<(N + 63) / 64, 256, 0, stream>>>(feat, meanf, W1s, W1n, b1,
                                                   W2n, W2s, t2, s2);
  gather2_final_kernel<<<(N * 4 + 255) / 256, 256, 0, stream>>>(ptr, col, t2, s2,
                                                                b2, out);
}

// Round 8
// 204.384 us; speedup vs baseline: 2.5361x; 1.1154x over previous
//
#include <hip/hip_runtime.h>

#define N_NODES 100000
#define N_EDGES 1600000
#define IN_F 32
#define HID_F 64
#define OUT_F 16
#define BSIZE 512                    // nodes per bucket (bucket = dst >> 9)
#define NBKT 256                     // slab slots (196 used)
#define CAP 10240                    // edge capacity per bucket slab (mean 8192, sigma~90)
#define CHUNK 4096                   // edges per block in bucket-sort pass
#define NBUCK ((N_NODES + BSIZE - 1) / BSIZE)   // 196
#define APITCH 68                    // padded pitch for transposed A / h1 tiles

// ---------------- slab cursor init: cursor[b] = b*CAP ----------------
__global__ __launch_bounds__(NBKT) void cursor_init_kernel(int* __restrict__ cursor) {
  cursor[threadIdx.x] = threadIdx.x * CAP;
}

// ---------------- one-pass LDS-staged bucket sort of edges by dst>>9 ----------------
__global__ __launch_bounds__(256) void bucket_kernel(
    const int* __restrict__ src, const int* __restrict__ dst,
    int* __restrict__ cursor, uint2* __restrict__ sorted) {
  __shared__ uint2 stage[CHUNK];         // 32 KB
  __shared__ int lcnt[NBKT], lscan[NBKT], gbase[NBKT];
  int t = threadIdx.x;
  lcnt[t] = 0;
  __syncthreads();

  int base = blockIdx.x * CHUNK;
  uint2 mypair[CHUNK / 256];
  int myb[CHUNK / 256], myrank[CHUNK / 256];
#pragma unroll
  for (int i = 0; i < CHUNK / 256; ++i) {
    int e = base + t + 256 * i;
    if (e < N_EDGES) {
      int s = src[e], d = dst[e];
      mypair[i].x = (unsigned)s;
      mypair[i].y = (unsigned)d;
      myb[i] = d >> 9;
      myrank[i] = atomicAdd(&lcnt[myb[i]], 1);
    } else {
      myb[i] = -1;
    }
  }
  __syncthreads();
  lscan[t] = lcnt[t];
  __syncthreads();
  for (int off = 1; off < NBKT; off <<= 1) {
    int v = (t >= off) ? lscan[t - off] : 0;
    __syncthreads();
    lscan[t] += v;
    __syncthreads();
  }
  gbase[t] = lcnt[t] ? atomicAdd(&cursor[t], lcnt[t]) : 0;
  __syncthreads();
#pragma unroll
  for (int i = 0; i < CHUNK / 256; ++i) {
    if (myb[i] >= 0) {
      int slot = (lscan[myb[i]] - lcnt[myb[i]]) + myrank[i];
      stage[slot] = mypair[i];
    }
  }
  __syncthreads();
  int nvalid = min(CHUNK, N_EDGES - base);
  for (int i = t; i < nvalid; i += 256) {
    uint2 p = stage[i];
    int b = (int)(p.y >> 9);
    int addr = gbase[b] + (i - (lscan[b] - lcnt[b]));
    sorted[addr] = p;
  }
}

// ---------------- per-bucket exact CSR build in LDS; 196 blocks, 1 node/thread ----------------
// ptr[v] = slab-relative inclusive end; col filled within bucket's slab window.
__global__ __launch_bounds__(512) void bcsr_kernel(
    const uint2* __restrict__ sorted, const int* __restrict__ cursor,
    int* __restrict__ ptr, int* __restrict__ col) {
  __shared__ int lcnt[BSIZE];      // 2 KB
  __shared__ int lcur[BSIZE];      // 2 KB
  __shared__ int scanbuf[BSIZE];   // 2 KB
  int t = threadIdx.x;
  int b = blockIdx.x;
  int base = b * CAP;
  int ne = cursor[b] - base;       // bucket_kernel left cursor[b] == base + count

  lcnt[t] = 0;
  __syncthreads();
  for (int i = t; i < ne; i += 512)
    atomicAdd(&lcnt[sorted[base + i].y & (BSIZE - 1)], 1);
  __syncthreads();

  int c = lcnt[t];
  scanbuf[t] = c;
  __syncthreads();
  for (int off = 1; off < 512; off <<= 1) {
    int u = (t >= off) ? scanbuf[t - off] : 0;
    __syncthreads();
    scanbuf[t] += u;
    __syncthreads();
  }
  int incl = scanbuf[t];
  lcur[t] = base + incl - c;       // start cursor
  int v = b * BSIZE + t;
  if (v < N_NODES) ptr[v] = base + incl;   // inclusive end (slab-relative)
  __syncthreads();

  for (int i = t; i < ne; i += 512) {
    uint2 p = sorted[base + i];
    int pos = atomicAdd(&lcur[p.y & (BSIZE - 1)], 1);
    col[pos] = (int)p.x;
  }
}

// ---------------- layer 1 aggregate: float4 gather, 8 lanes/node ----------------
__global__ __launch_bounds__(256) void gather1_kernel(
    const int* __restrict__ ptr, const int* __restrict__ col,
    const float* __restrict__ feat, float* __restrict__ meanf) {
  int gid = blockIdx.x * 256 + threadIdx.x;
  int v = gid >> 3;
  int f4 = gid & 7;
  int start = (v & (BSIZE - 1)) ? ptr[v - 1] : (v >> 9) * CAP;
  int end = ptr[v];
  const float4* F = (const float4*)feat;
  float4 s0 = {0.f, 0.f, 0.f, 0.f}, s1 = {0.f, 0.f, 0.f, 0.f};
  int e = start;
  for (; e + 1 < end; e += 2) {
    int c0 = col[e], c1 = col[e + 1];
    float4 a = F[c0 * 8 + f4];
    float4 b = F[c1 * 8 + f4];
    s0.x += a.x; s0.y += a.y; s0.z += a.z; s0.w += a.w;
    s1.x += b.x; s1.y += b.y; s1.z += b.z; s1.w += b.w;
  }
  if (e < end) {
    float4 a = F[col[e] * 8 + f4];
    s0.x += a.x; s0.y += a.y; s0.z += a.z; s0.w += a.w;
  }
  float inv = 1.0f / fmaxf((float)(end - start), 1.0f);
  float4 r;
  r.x = (s0.x + s1.x) * inv; r.y = (s0.y + s1.y) * inv;
  r.z = (s0.z + s1.z) * inv; r.w = (s0.w + s1.w) * inv;
  ((float4*)meanf)[v * 8 + f4] = r;
}

// ------- fused register-tiled GEMM: h1 = relu([feat|meanf] @ [W1s;W1n] + b1);
//         t2 = h1 @ W2n, s2 = h1 @ W2s. 4x4 tile/thread phase 1, 4x2 phase 2. -------
__global__ __launch_bounds__(256) void l1t2s2_kernel(
    const float* __restrict__ feat, const float* __restrict__ meanf,
    const float* __restrict__ W1s, const float* __restrict__ W1n,
    const float* __restrict__ b1,
    const float* __restrict__ W2n, const float* __restrict__ W2s,
    float* __restrict__ t2, float* __restrict__ s2) {
  __shared__ float sA[64 * APITCH];   // A^T: sA[k][n], 17 KB
  __shared__ float sW[64 * 64];       // W: sW[k][c], 16 KB; phase 2 reuses as [64][32]

  int t = threadIdx.x;
  int tile = blockIdx.x * 64;
  int nvalid = min(64, N_NODES - tile);

  {
    const float4* Fg = (const float4*)(feat + (size_t)tile * IN_F);
    const float4* Mg = (const float4*)(meanf + (size_t)tile * IN_F);
    int lim = nvalid * 8;
#pragma unroll
    for (int it = 0; it < 2; ++it) {
      int idx = t + 256 * it;
      int n = idx >> 3, c = idx & 7;
      if (idx < lim) {
        float4 a = Fg[idx];
        sA[(4 * c + 0) * APITCH + n] = a.x;
        sA[(4 * c + 1) * APITCH + n] = a.y;
        sA[(4 * c + 2) * APITCH + n] = a.z;
        sA[(4 * c + 3) * APITCH + n] = a.w;
        float4 m = Mg[idx];
        sA[(32 + 4 * c + 0) * APITCH + n] = m.x;
        sA[(32 + 4 * c + 1) * APITCH + n] = m.y;
        sA[(32 + 4 * c + 2) * APITCH + n] = m.z;
        sA[(32 + 4 * c + 3) * APITCH + n] = m.w;
      }
    }
  }
  {
    float4* Ws = (float4*)sW;
#pragma unroll
    for (int it = 0; it < 4; ++it) {
      int idx = t + 256 * it;
      int row = idx >> 4;
      const float4* srcw = (row < 32) ? (const float4*)W1s : (const float4*)W1n;
      Ws[idx] = srcw[(row & 31) * 16 + (idx & 15)];
    }
  }
  int tx = t & 15, ty = t >> 4;
  int n0 = 4 * ty, c0 = 4 * tx;
  float4 bb = ((const float4*)b1)[tx];
  __syncthreads();

  float acc[4][4];
#pragma unroll
  for (int i = 0; i < 4; ++i) { acc[i][0] = bb.x; acc[i][1] = bb.y; acc[i][2] = bb.z; acc[i][3] = bb.w; }
#pragma unroll 4
  for (int k = 0; k < 64; ++k) {
    float4 a = *(const float4*)&sA[k * APITCH + n0];
    float4 w = *(const float4*)&sW[k * 64 + c0];
    acc[0][0] += a.x * w.x; acc[0][1] += a.x * w.y; acc[0][2] += a.x * w.z; acc[0][3] += a.x * w.w;
    acc[1][0] += a.y * w.x; acc[1][1] += a.y * w.y; acc[1][2] += a.y * w.z; acc[1][3] += a.y * w.w;
    acc[2][0] += a.z * w.x; acc[2][1] += a.z * w.y; acc[2][2] += a.z * w.z; acc[2][3] += a.z * w.w;
    acc[3][0] += a.w * w.x; acc[3][1] += a.w * w.y; acc[3][2] += a.w * w.z; acc[3][3] += a.w * w.w;
  }
  __syncthreads();

#pragma unroll
  for (int jj = 0; jj < 4; ++jj) {
    float4 v;
    v.x = fmaxf(acc[0][jj], 0.0f);
    v.y = fmaxf(acc[1][jj], 0.0f);
    v.z = fmaxf(acc[2][jj], 0.0f);
    v.w = fmaxf(acc[3][jj], 0.0f);
    *(float4*)&sA[(c0 + jj) * APITCH + n0] = v;   // h1^T[j][n]
  }
  {
    float4* Ws = (float4*)sW;
#pragma unroll
    for (int it = 0; it < 2; ++it) {
      int idx = t + 256 * it;
      int row = idx >> 3, ch = idx & 7;
      const float4* srcw = (ch < 4) ? (const float4*)W2n : (const float4*)W2s;
      Ws[row * 8 + ch] = srcw[row * 4 + (ch & 3)];
    }
  }
  __syncthreads();

  int c2 = 2 * tx;
  float a0 = 0.f, a1 = 0.f, b0 = 0.f, b1_ = 0.f, d0 = 0.f, d1 = 0.f, e0 = 0.f, e1 = 0.f;
#pragma unroll 4
  for (int k = 0; k < 64; ++k) {
    float4 a = *(const float4*)&sA[k * APITCH + n0];
    float2 w = *(const float2*)&sW[k * 32 + c2];
    a0 += a.x * w.x; a1 += a.x * w.y;
    b0 += a.y * w.x; b1_ += a.y * w.y;
    d0 += a.z * w.x; d1 += a.z * w.y;
    e0 += a.w * w.x; e1 += a.w * w.y;
  }
  {
    float rs[4][2] = {{a0, a1}, {b0, b1_}, {d0, d1}, {e0, e1}};
    float* outp = (c2 < 16) ? t2 : s2;
    int cc = c2 & 15;
#pragma unroll
    for (int i = 0; i < 4; ++i) {
      int v = tile + n0 + i;
      if (v < N_NODES) *(float2*)&outp[v * OUT_F + cc] = make_float2(rs[i][0], rs[i][1]);
    }
  }
}

// ---------------- layer 2 aggregate + final: float4, 4 lanes/node ----------------
__global__ __launch_bounds__(256) void gather2_final_kernel(
    const int* __restrict__ ptr, const int* __restrict__ col,
    const float* __restrict__ t2, const float* __restrict__ s2,
    const float* __restrict__ b2, float* __restrict__ out) {
  int gid = blockIdx.x * 256 + threadIdx.x;
  int v = gid >> 2;
  int c4 = gid & 3;
  if (v >= N_NODES) return;
  int start = (v & (BSIZE - 1)) ? ptr[v - 1] : (v >> 9) * CAP;
  int end = ptr[v];
  const float4* T = (const float4*)t2;
  float4 a0 = {0.f, 0.f, 0.f, 0.f}, a1 = {0.f, 0.f, 0.f, 0.f};
  int e = start;
  for (; e + 1 < end; e += 2) {
    int c0 = col[e], c1 = col[e + 1];
    float4 x = T[c0 * 4 + c4];
    float4 y = T[c1 * 4 + c4];
    a0.x += x.x; a0.y += x.y; a0.z += x.z; a0.w += x.w;
    a1.x += y.x; a1.y += y.y; a1.z += y.z; a1.w += y.w;
  }
  if (e < end) {
    float4 x = T[col[e] * 4 + c4];
    a0.x += x.x; a0.y += x.y; a0.z += x.z; a0.w += x.w;
  }
  float inv = 1.0f / fmaxf((float)(end - start), 1.0f);
  float4 sv = ((const float4*)s2)[v * 4 + c4];
  float4 bv = ((const float4*)b2)[c4];
  float4 r;
  r.x = sv.x + bv.x + (a0.x + a1.x) * inv;
  r.y = sv.y + bv.y + (a0.y + a1.y) * inv;
  r.z = sv.z + bv.z + (a0.z + a1.z) * inv;
  r.w = sv.w + bv.w + (a0.w + a1.w) * inv;
  ((float4*)out)[v * 4 + c4] = r;
}

extern "C" void kernel_launch(void* const* d_in, const int* in_sizes, int n_in,
                              void* d_out, int out_size, void* d_ws, size_t ws_size,
                              hipStream_t stream) {
  const float* feat = (const float*)d_in[0];
  const int* src    = (const int*)d_in[1];
  const int* dst    = (const int*)d_in[2];
  const float* W1s  = (const float*)d_in[3];
  const float* W1n  = (const float*)d_in[4];
  const float* b1   = (const float*)d_in[5];
  const float* W2s  = (const float*)d_in[6];
  const float* W2n  = (const float*)d_in[7];
  const float* b2   = (const float*)d_in[8];
  float* out = (float*)d_out;

  const size_t N = N_NODES;
  const size_t SLAB = (size_t)NBKT * CAP;   // 2.62M entries
  // workspace layout (~58 MB, un-aliased for clean profiling)
  int* ptr = (int*)d_ws;                    // N (+8 pad)
  int* col = ptr + N + 8;                   // SLAB ints   (10.5 MB)
  uint2* sorted = (uint2*)(col + SLAB);     // SLAB uint2  (21 MB)
  float* meanf = (float*)(sorted + SLAB);   // 32N
  float* t2 = meanf + 32 * N;               // 16N
  float* s2 = t2 + 16 * N;                  // 16N
  int* cursor = (int*)(s2 + 16 * N);        // NBKT

  cursor_init_kernel<<<1, NBKT, 0, stream>>>(cursor);
  bucket_kernel<<<(N_EDGES + CHUNK - 1) / CHUNK, 256, 0, stream>>>(src, dst, cursor, sorted);
  bcsr_kernel<<<NBUCK, 512, 0, stream>>>(sorted, cursor, ptr, col);

  gather1_kernel<<<N_NODES * 8 / 256, 256, 0, stream>>>(ptr, col, feat, meanf);
  l1t2s2_kernel<<<(N_NODES + 63) / 64, 256, 0, stream>>>(feat, meanf, W1s, W1n, b1,
                                                         W2n, W2s, t2, s2);
  gather2_final_kernel<<<(N_NODES * 4 + 255) / 256, 256, 0, stream>>>(ptr, col, t2, s2,
                                                                      b2, out);
}

// Round 9
// 203.430 us; speedup vs baseline: 2.5480x; 1.0047x over previous
//
#include <hip/hip_runtime.h>

#define N_NODES 100000
#define N_EDGES 1600000
#define IN_F 32
#define HID_F 64
#define OUT_F 16
#define BSIZE 512                    // nodes per bucket (bucket = dst >> 9)
#define NBKT 256                     // slab slots (196 used)
#define CAP 10240                    // edge capacity per bucket slab (mean 8192)
#define CHUNK 4096                   // edges per block in bucket-sort pass
#define NBUCK ((N_NODES + BSIZE - 1) / BSIZE)   // 196
#define APITCH 68                    // padded pitch for transposed A / h1 tiles

// ---------------- slab cursor init: cursor[b] = b*CAP ----------------
__global__ __launch_bounds__(NBKT) void cursor_init_kernel(int* __restrict__ cursor) {
  cursor[threadIdx.x] = threadIdx.x * CAP;
}

// ---------------- one-pass LDS-staged bucket sort; packed (src<<9)|dstLocal ----------------
__global__ __launch_bounds__(256) void bucket_kernel(
    const int* __restrict__ src, const int* __restrict__ dst,
    int* __restrict__ cursor, unsigned* __restrict__ sorted) {
  __shared__ unsigned stage[CHUNK];        // 16 KB
  __shared__ unsigned char sbkt[CHUNK];    // 4 KB
  __shared__ int lcnt[NBKT], lscan[NBKT], gbase[NBKT];
  int t = threadIdx.x;
  lcnt[t] = 0;
  __syncthreads();

  int base = blockIdx.x * CHUNK;
  unsigned mypk[CHUNK / 256];
  int myb[CHUNK / 256], myrank[CHUNK / 256];
#pragma unroll
  for (int i = 0; i < CHUNK / 256; ++i) {
    int e = base + t + 256 * i;
    if (e < N_EDGES) {
      unsigned s = (unsigned)src[e], d = (unsigned)dst[e];
      myb[i] = (int)(d >> 9);
      mypk[i] = (s << 9) | (d & 511u);
      myrank[i] = atomicAdd(&lcnt[myb[i]], 1);
    } else {
      myb[i] = -1;
    }
  }
  __syncthreads();
  lscan[t] = lcnt[t];
  __syncthreads();
  for (int off = 1; off < NBKT; off <<= 1) {
    int v = (t >= off) ? lscan[t - off] : 0;
    __syncthreads();
    lscan[t] += v;
    __syncthreads();
  }
  gbase[t] = lcnt[t] ? atomicAdd(&cursor[t], lcnt[t]) : 0;
  __syncthreads();
#pragma unroll
  for (int i = 0; i < CHUNK / 256; ++i) {
    if (myb[i] >= 0) {
      int slot = (lscan[myb[i]] - lcnt[myb[i]]) + myrank[i];
      stage[slot] = mypk[i];
      sbkt[slot] = (unsigned char)myb[i];
    }
  }
  __syncthreads();
  int nvalid = min(CHUNK, N_EDGES - base);
  for (int i = t; i < nvalid; i += 256) {
    unsigned p = stage[i];
    int b = (int)sbkt[i];
    int addr = gbase[b] + (i - (lscan[b] - lcnt[b]));
    sorted[addr] = p;
  }
}

// ---------------- per-bucket exact CSR build in LDS; 196 blocks, 1 node/thread ----------------
// ptr[v] = slab-relative inclusive end; col filled within bucket's slab window.
__global__ __launch_bounds__(512) void bcsr_kernel(
    const unsigned* __restrict__ sorted, const int* __restrict__ cursor,
    int* __restrict__ ptr, int* __restrict__ col) {
  __shared__ int lcnt[BSIZE];      // 2 KB
  __shared__ int lcur[BSIZE];      // 2 KB
  __shared__ int scanbuf[BSIZE];   // 2 KB
  int t = threadIdx.x;
  int b = blockIdx.x;
  int base = b * CAP;
  int ne = cursor[b] - base;       // bucket_kernel left cursor[b] == base + count

  lcnt[t] = 0;
  __syncthreads();
  for (int i = t; i < ne; i += 512)
    atomicAdd(&lcnt[sorted[base + i] & (BSIZE - 1)], 1);
  __syncthreads();

  int c = lcnt[t];
  scanbuf[t] = c;
  __syncthreads();
  for (int off = 1; off < 512; off <<= 1) {
    int u = (t >= off) ? scanbuf[t - off] : 0;
    __syncthreads();
    scanbuf[t] += u;
    __syncthreads();
  }
  int incl = scanbuf[t];
  lcur[t] = base + incl - c;       // start cursor
  int v = b * BSIZE + t;
  if (v < N_NODES) ptr[v] = base + incl;   // inclusive end (slab-relative)
  __syncthreads();

  for (int i = t; i < ne; i += 512) {
    unsigned p = sorted[base + i];
    int pos = atomicAdd(&lcur[p & (BSIZE - 1)], 1);
    col[pos] = (int)(p >> 9);
  }
}

// ---------------- layer 1 aggregate: float4 gather, 8 lanes/node, 4-deep MLP ----------------
__global__ __launch_bounds__(256) void gather1_kernel(
    const int* __restrict__ ptr, const int* __restrict__ col,
    const float* __restrict__ feat, float* __restrict__ meanf) {
  int gid = blockIdx.x * 256 + threadIdx.x;
  int v = gid >> 3;
  int f4 = gid & 7;
  int start = (v & (BSIZE - 1)) ? ptr[v - 1] : (v >> 9) * CAP;
  int end = ptr[v];
  const float4* F = (const float4*)feat;
  float4 s0 = {0.f, 0.f, 0.f, 0.f}, s1 = {0.f, 0.f, 0.f, 0.f};
  float4 s2 = {0.f, 0.f, 0.f, 0.f}, s3 = {0.f, 0.f, 0.f, 0.f};
  int e = start;
  for (; e + 3 < end; e += 4) {
    int c0 = col[e], c1 = col[e + 1], c2 = col[e + 2], c3 = col[e + 3];
    float4 a = F[c0 * 8 + f4];
    float4 b = F[c1 * 8 + f4];
    float4 cc = F[c2 * 8 + f4];
    float4 d = F[c3 * 8 + f4];
    s0.x += a.x; s0.y += a.y; s0.z += a.z; s0.w += a.w;
    s1.x += b.x; s1.y += b.y; s1.z += b.z; s1.w += b.w;
    s2.x += cc.x; s2.y += cc.y; s2.z += cc.z; s2.w += cc.w;
    s3.x += d.x; s3.y += d.y; s3.z += d.z; s3.w += d.w;
  }
  for (; e < end; ++e) {
    float4 a = F[col[e] * 8 + f4];
    s0.x += a.x; s0.y += a.y; s0.z += a.z; s0.w += a.w;
  }
  float inv = 1.0f / fmaxf((float)(end - start), 1.0f);
  float4 r;
  r.x = (s0.x + s1.x + s2.x + s3.x) * inv;
  r.y = (s0.y + s1.y + s2.y + s3.y) * inv;
  r.z = (s0.z + s1.z + s2.z + s3.z) * inv;
  r.w = (s0.w + s1.w + s2.w + s3.w) * inv;
  ((float4*)meanf)[v * 8 + f4] = r;
}

// ------- fused register-tiled GEMM: h1 = relu([feat|meanf] @ [W1s;W1n] + b1);
//         t2 = h1 @ W2n, s2 = h1 @ W2s. 4x4 tile/thread phase 1, 4x2 phase 2. -------
__global__ __launch_bounds__(256) void l1t2s2_kernel(
    const float* __restrict__ feat, const float* __restrict__ meanf,
    const float* __restrict__ W1s, const float* __restrict__ W1n,
    const float* __restrict__ b1,
    const float* __restrict__ W2n, const float* __restrict__ W2s,
    float* __restrict__ t2, float* __restrict__ s2) {
  __shared__ float sA[64 * APITCH];   // A^T: sA[k][n], 17 KB
  __shared__ float sW[64 * 64];       // W: sW[k][c], 16 KB; phase 2 reuses as [64][32]

  int t = threadIdx.x;
  int tile = blockIdx.x * 64;
  int nvalid = min(64, N_NODES - tile);

  {
    const float4* Fg = (const float4*)(feat + (size_t)tile * IN_F);
    const float4* Mg = (const float4*)(meanf + (size_t)tile * IN_F);
    int lim = nvalid * 8;
#pragma unroll
    for (int it = 0; it < 2; ++it) {
      int idx = t + 256 * it;
      int n = idx >> 3, c = idx & 7;
      if (idx < lim) {
        float4 a = Fg[idx];
        sA[(4 * c + 0) * APITCH + n] = a.x;
        sA[(4 * c + 1) * APITCH + n] = a.y;
        sA[(4 * c + 2) * APITCH + n] = a.z;
        sA[(4 * c + 3) * APITCH + n] = a.w;
        float4 m = Mg[idx];
        sA[(32 + 4 * c + 0) * APITCH + n] = m.x;
        sA[(32 + 4 * c + 1) * APITCH + n] = m.y;
        sA[(32 + 4 * c + 2) * APITCH + n] = m.z;
        sA[(32 + 4 * c + 3) * APITCH + n] = m.w;
      }
    }
  }
  {
    float4* Ws = (float4*)sW;
#pragma unroll
    for (int it = 0; it < 4; ++it) {
      int idx = t + 256 * it;
      int row = idx >> 4;
      const float4* srcw = (row < 32) ? (const float4*)W1s : (const float4*)W1n;
      Ws[idx] = srcw[(row & 31) * 16 + (idx & 15)];
    }
  }
  int tx = t & 15, ty = t >> 4;
  int n0 = 4 * ty, c0 = 4 * tx;
  float4 bb = ((const float4*)b1)[tx];
  __syncthreads();

  float acc[4][4];
#pragma unroll
  for (int i = 0; i < 4; ++i) { acc[i][0] = bb.x; acc[i][1] = bb.y; acc[i][2] = bb.z; acc[i][3] = bb.w; }
#pragma unroll 4
  for (int k = 0; k < 64; ++k) {
    float4 a = *(const float4*)&sA[k * APITCH + n0];
    float4 w = *(const float4*)&sW[k * 64 + c0];
    acc[0][0] += a.x * w.x; acc[0][1] += a.x * w.y; acc[0][2] += a.x * w.z; acc[0][3] += a.x * w.w;
    acc[1][0] += a.y * w.x; acc[1][1] += a.y * w.y; acc[1][2] += a.y * w.z; acc[1][3] += a.y * w.w;
    acc[2][0] += a.z * w.x; acc[2][1] += a.z * w.y; acc[2][2] += a.z * w.z; acc[2][3] += a.z * w.w;
    acc[3][0] += a.w * w.x; acc[3][1] += a.w * w.y; acc[3][2] += a.w * w.z; acc[3][3] += a.w * w.w;
  }
  __syncthreads();

#pragma unroll
  for (int jj = 0; jj < 4; ++jj) {
    float4 v;
    v.x = fmaxf(acc[0][jj], 0.0f);
    v.y = fmaxf(acc[1][jj], 0.0f);
    v.z = fmaxf(acc[2][jj], 0.0f);
    v.w = fmaxf(acc[3][jj], 0.0f);
    *(float4*)&sA[(c0 + jj) * APITCH + n0] = v;   // h1^T[j][n]
  }
  {
    float4* Ws = (float4*)sW;
#pragma unroll
    for (int it = 0; it < 2; ++it) {
      int idx = t + 256 * it;
      int row = idx >> 3, ch = idx & 7;
      const float4* srcw = (ch < 4) ? (const float4*)W2n : (const float4*)W2s;
      Ws[row * 8 + ch] = srcw[row * 4 + (ch & 3)];
    }
  }
  __syncthreads();

  int c2 = 2 * tx;
  float a0 = 0.f, a1 = 0.f, b0 = 0.f, b1_ = 0.f, d0 = 0.f, d1 = 0.f, e0 = 0.f, e1 = 0.f;
#pragma unroll 4
  for (int k = 0; k < 64; ++k) {
    float4 a = *(const float4*)&sA[k * APITCH + n0];
    float2 w = *(const float2*)&sW[k * 32 + c2];
    a0 += a.x * w.x; a1 += a.x * w.y;
    b0 += a.y * w.x; b1_ += a.y * w.y;
    d0 += a.z * w.x; d1 += a.z * w.y;
    e0 += a.w * w.x; e1 += a.w * w.y;
  }
  {
    float rs[4][2] = {{a0, a1}, {b0, b1_}, {d0, d1}, {e0, e1}};
    float* outp = (c2 < 16) ? t2 : s2;
    int cc = c2 & 15;
#pragma unroll
    for (int i = 0; i < 4; ++i) {
      int v = tile + n0 + i;
      if (v < N_NODES) *(float2*)&outp[v * OUT_F + cc] = make_float2(rs[i][0], rs[i][1]);
    }
  }
}

// ---------------- layer 2 aggregate + final: float4, 4 lanes/node, 4-deep MLP ----------------
__global__ __launch_bounds__(256) void gather2_final_kernel(
    const int* __restrict__ ptr, const int* __restrict__ col,
    const float* __restrict__ t2, const float* __restrict__ s2,
    const float* __restrict__ b2, float* __restrict__ out) {
  int gid = blockIdx.x * 256 + threadIdx.x;
  int v = gid >> 2;
  int c4 = gid & 3;
  if (v >= N_NODES) return;
  int start = (v & (BSIZE - 1)) ? ptr[v - 1] : (v >> 9) * CAP;
  int end = ptr[v];
  const float4* T = (const float4*)t2;
  float4 a0 = {0.f, 0.f, 0.f, 0.f}, a1 = {0.f, 0.f, 0.f, 0.f};
  float4 a2 = {0.f, 0.f, 0.f, 0.f}, a3 = {0.f, 0.f, 0.f, 0.f};
  int e = start;
  for (; e + 3 < end; e += 4) {
    int c0 = col[e], c1 = col[e + 1], c2 = col[e + 2], c3 = col[e + 3];
    float4 x = T[c0 * 4 + c4];
    float4 y = T[c1 * 4 + c4];
    float4 z = T[c2 * 4 + c4];
    float4 w = T[c3 * 4 + c4];
    a0.x += x.x; a0.y += x.y; a0.z += x.z; a0.w += x.w;
    a1.x += y.x; a1.y += y.y; a1.z += y.z; a1.w += y.w;
    a2.x += z.x; a2.y += z.y; a2.z += z.z; a2.w += z.w;
    a3.x += w.x; a3.y += w.y; a3.z += w.z; a3.w += w.w;
  }
  for (; e < end; ++e) {
    float4 x = T[col[e] * 4 + c4];
    a0.x += x.x; a0.y += x.y; a0.z += x.z; a0.w += x.w;
  }
  float inv = 1.0f / fmaxf((float)(end - start), 1.0f);
  float4 sv = ((const float4*)s2)[v * 4 + c4];
  float4 bv = ((const float4*)b2)[c4];
  float4 r;
  r.x = sv.x + bv.x + (a0.x + a1.x + a2.x + a3.x) * inv;
  r.y = sv.y + bv.y + (a0.y + a1.y + a2.y + a3.y) * inv;
  r.z = sv.z + bv.z + (a0.z + a1.z + a2.z + a3.z) * inv;
  r.w = sv.w + bv.w + (a0.w + a1.w + a2.w + a3.w) * inv;
  ((float4*)out)[v * 4 + c4] = r;
}

extern "C" void kernel_launch(void* const* d_in, const int* in_sizes, int n_in,
                              void* d_out, int out_size, void* d_ws, size_t ws_size,
                              hipStream_t stream) {
  const float* feat = (const float*)d_in[0];
  const int* src    = (const int*)d_in[1];
  const int* dst    = (const int*)d_in[2];
  const float* W1s  = (const float*)d_in[3];
  const float* W1n  = (const float*)d_in[4];
  const float* b1   = (const float*)d_in[5];
  const float* W2s  = (const float*)d_in[6];
  const float* W2n  = (const float*)d_in[7];
  const float* b2   = (const float*)d_in[8];
  float* out = (float*)d_out;

  const size_t N = N_NODES;
  const size_t SLAB = (size_t)NBKT * CAP;   // 2.62M entries
  // workspace layout (~47 MB, un-aliased)
  int* ptr = (int*)d_ws;                    // N (+8 pad)
  int* col = ptr + N + 8;                   // SLAB ints      (10.5 MB)
  unsigned* sorted = (unsigned*)(col + SLAB);  // SLAB uint32 (10.5 MB)
  float* meanf = (float*)(sorted + SLAB);   // 32N
  float* t2 = meanf + 32 * N;               // 16N
  float* s2 = t2 + 16 * N;                  // 16N
  int* cursor = (int*)(s2 + 16 * N);        // NBKT

  cursor_init_kernel<<<1, NBKT, 0, stream>>>(cursor);
  bucket_kernel<<<(N_EDGES + CHUNK - 1) / CHUNK, 256, 0, stream>>>(src, dst, cursor, sorted);
  bcsr_kernel<<<NBUCK, 512, 0, stream>>>(sorted, cursor, ptr, col);

  gather1_kernel<<<N_NODES * 8 / 256, 256, 0, stream>>>(ptr, col, feat, meanf);
  l1t2s2_kernel<<<(N_NODES + 63) / 64, 256, 0, stream>>>(feat, meanf, W1s, W1n, b1,
                                                         W2n, W2s, t2, s2);
  gather2_final_kernel<<<(N_NODES * 4 + 255) / 256, 256, 0, stream>>>(ptr, col, t2, s2,
                                                                      b2, out);
}